// Round 8
// baseline (1626.287 us; speedup 1.0000x reference)
//
#include <hip/hip_runtime.h>

// Problem dims
#define BDIM 32
#define NDIM 400
#define TDIM 315
#define TPAD 320
#define DDIM 512
#define HDIM 256
#define NITER 100

// Workspace layout (bytes)
#define OFS_TA    0u          // tA[320][512] f32 = 655360
#define OFS_TB    1048576u    // TB[320][256] f32 = 327680   (text @ Wh_bot + bh)
#define OFS_STATS 1572864u    // stats[32][2] f32 = 256      (sum, sumsq per batch)
#define OFS_S     2097152u    // s/s1[32][400][320] f32 = 16384000
#define OFS_F1    18874368u   // f1[32][315][512] f32 = 20643840
#define OFS_H     41943040u   // h[10080][256] f32 = 10321920

// ---------------- shared GEMM pieces: 64x64 tile, BK=32, 256 thr, 4x4 micro ----------------

__device__ __forceinline__ void mm_inner(const float* __restrict__ As, const float* __restrict__ Bs,
                                         float acc[4][4], int tm, int tn) {
#pragma unroll
  for (int k = 0; k < 32; ++k) {
    float4 a = *(const float4*)(As + k * 72 + tm * 4);
    float4 b = *(const float4*)(Bs + k * 72 + tn * 4);
    float ar[4] = {a.x, a.y, a.z, a.w};
    float br[4] = {b.x, b.y, b.z, b.w};
#pragma unroll
    for (int i = 0; i < 4; ++i)
#pragma unroll
      for (int j = 0; j < 4; ++j)
        acc[i][j] = fmaf(ar[i], br[j], acc[i][j]);
  }
}

// Stage X[row][k] (K-contiguous rows) transposed into Xs[k][m]; rows >= rmax -> 0
__device__ __forceinline__ void stage_T(float* __restrict__ Xs, const float* __restrict__ X,
                                        int r0, int ld, int k0, int tid, int rmax) {
  int kq = tid & 7;   // float4 group along K
  int mb = tid >> 3;  // 0..31
#pragma unroll
  for (int p = 0; p < 2; ++p) {
    int mm = mb + 32 * p;
    int row = r0 + mm;
    float4 v = make_float4(0.f, 0.f, 0.f, 0.f);
    if (row < rmax) v = *(const float4*)(X + (size_t)row * ld + k0 + 4 * kq);
    Xs[(4 * kq + 0) * 72 + mm] = v.x;
    Xs[(4 * kq + 1) * 72 + mm] = v.y;
    Xs[(4 * kq + 2) * 72 + mm] = v.z;
    Xs[(4 * kq + 3) * 72 + mm] = v.w;
  }
}

// Stage W[k][n] (N-contiguous rows) into Ws[k][j]; k0+k >= kmax -> 0
__device__ __forceinline__ void stage_N(float* __restrict__ Ws, const float* __restrict__ W,
                                        int k0, int ld, int n0, int tid, int kmax) {
  int nq = tid & 15;
  int kk = tid >> 4;  // 0..15
#pragma unroll
  for (int p = 0; p < 2; ++p) {
    int k = kk + 16 * p;
    float4 v = make_float4(0.f, 0.f, 0.f, 0.f);
    if (k0 + k < kmax) v = *(const float4*)(W + (size_t)(k0 + k) * ld + n0 + 4 * nq);
    *(float4*)(Ws + k * 72 + 4 * nq) = v;
  }
}

// ---------------- K1a: tA[t][d] = sum_e text[t][e] * A[d][e]  (NT) ----------------
__global__ void k_tA(const float* __restrict__ text, const float* __restrict__ A,
                     float* __restrict__ tA) {
  __shared__ float Xs[32 * 72], Ys[32 * 72];
  int tid = threadIdx.x, tm = tid >> 4, tn = tid & 15;
  int d0 = blockIdx.x * 64, t0 = blockIdx.y * 64;
  float acc[4][4] = {};
  for (int k0 = 0; k0 < 512; k0 += 32) {
    stage_T(Xs, text, t0, 512, k0, tid, TDIM);
    stage_T(Ys, A, d0, 512, k0, tid, 512);
    __syncthreads();
    mm_inner(Xs, Ys, acc, tm, tn);
    __syncthreads();
  }
#pragma unroll
  for (int i = 0; i < 4; ++i) {
    int t = t0 + tm * 4 + i;  // pad rows get zeros (Xs zero-filled)
    *(float4*)(tA + (size_t)t * 512 + d0 + tn * 4) =
        make_float4(acc[i][0], acc[i][1], acc[i][2], acc[i][3]);
  }
}

// ---------------- K1b: TB[t][h] = text[t]. @ Wh_bot + bh  (NN) ----------------
__global__ void k_TB(const float* __restrict__ text, const float* __restrict__ Wh,
                     const float* __restrict__ bh, float* __restrict__ TB) {
  __shared__ float Xs[32 * 72], Ws[32 * 72];
  int tid = threadIdx.x, tm = tid >> 4, tn = tid & 15;
  int h0 = blockIdx.x * 64, t0 = blockIdx.y * 64;
  const float* Wb = Wh + 512 * 256;  // bottom half rows of Wh[1024][256]
  float acc[4][4] = {};
  for (int k0 = 0; k0 < 512; k0 += 32) {
    stage_T(Xs, text, t0, 512, k0, tid, TDIM);
    stage_N(Ws, Wb, k0, 256, h0, tid, 512);
    __syncthreads();
    mm_inner(Xs, Ws, acc, tm, tn);
    __syncthreads();
  }
#pragma unroll
  for (int i = 0; i < 4; ++i) {
    int t = t0 + tm * 4 + i;
    int h = h0 + tn * 4;
    *(float4*)(TB + (size_t)t * 256 + h) =
        make_float4(acc[i][0] + bh[h], acc[i][1] + bh[h + 1],
                    acc[i][2] + bh[h + 2], acc[i][3] + bh[h + 3]);
  }
}

// ---------------- K2: s[b][n][t] = F[b][n]. dot tA[t].  (NT) + instnorm stats ----------------
__global__ void k_s(const float* __restrict__ F, const float* __restrict__ tA,
                    float* __restrict__ s, float* __restrict__ stats) {
  __shared__ float Xs[32 * 72], Ys[32 * 72];
  __shared__ float red[8];
  int tid = threadIdx.x, tm = tid >> 4, tn = tid & 15;
  int t0 = blockIdx.x * 64, n0 = blockIdx.y * 64, bz = blockIdx.z;
  const float* Fb = F + (size_t)bz * NDIM * DDIM;
  float* sb = s + (size_t)bz * NDIM * TPAD;
  float acc[4][4] = {};
  for (int k0 = 0; k0 < 512; k0 += 32) {
    stage_T(Xs, Fb, n0, 512, k0, tid, NDIM);
    stage_T(Ys, tA, t0, 512, k0, tid, TPAD);  // pad rows of tA are zeros
    __syncthreads();
    mm_inner(Xs, Ys, acc, tm, tn);
    __syncthreads();
  }
  float lsum = 0.f, lsq = 0.f;
#pragma unroll
  for (int i = 0; i < 4; ++i) {
    int n = n0 + tm * 4 + i;
    if (n < NDIM) {
      int tb = t0 + tn * 4;
      if (tb + 3 < TDIM) {
        *(float4*)(sb + (size_t)n * TPAD + tb) =
            make_float4(acc[i][0], acc[i][1], acc[i][2], acc[i][3]);
#pragma unroll
        for (int j = 0; j < 4; ++j) { lsum += acc[i][j]; lsq = fmaf(acc[i][j], acc[i][j], lsq); }
      } else {
#pragma unroll
        for (int j = 0; j < 4; ++j) {
          int t = tb + j;
          if (t < TDIM) {
            sb[(size_t)n * TPAD + t] = acc[i][j];
            lsum += acc[i][j]; lsq = fmaf(acc[i][j], acc[i][j], lsq);
          }
        }
      }
    }
  }
#pragma unroll
  for (int m = 1; m <= 32; m <<= 1) {
    lsum += __shfl_xor(lsum, m, 64);
    lsq  += __shfl_xor(lsq, m, 64);
  }
  int wv = tid >> 6;
  if ((tid & 63) == 0) { red[wv * 2] = lsum; red[wv * 2 + 1] = lsq; }
  __syncthreads();
  if (tid == 0) {
    float S = red[0] + red[2] + red[4] + red[6];
    float Q = red[1] + red[3] + red[5] + red[7];
    atomicAdd(&stats[bz * 2], S);
    atomicAdd(&stats[bz * 2 + 1], Q);
  }
}

// ---------------- DPP wave-64 sum helpers (VALU pipe, no LDS) ----------------
template <int CTRL, int RMASK>
__device__ __forceinline__ float dppadd(float x) {
  int y = __builtin_amdgcn_update_dpp(0, __float_as_int(x), CTRL, RMASK, 0xf, true);
  return x + __int_as_float(y);
}

// ---------------- bf16 pack/unpack (RNE) ----------------
__device__ __forceinline__ unsigned rne_hi(float x) {
  unsigned u = __float_as_uint(x);
  u += 0x7fffu + ((u >> 16) & 1u);
  return u & 0xffff0000u;
}
__device__ __forceinline__ unsigned pack2(float lo, float hi) {
  return (rne_hi(lo) >> 16) | rne_hi(hi);
}
__device__ __forceinline__ float unpk_lo(unsigned p) { return __uint_as_float(p << 16); }
__device__ __forceinline__ float unpk_hi(unsigned p) { return __uint_as_float(p & 0xffff0000u); }

// ---------------- K3: fused instnorm finalize + sinkhorn (matrix scaling, early-exit) ----------
// 512 threads (8 waves). E stripes 0-1 in registers (50 bf16-packed uints), stripes 2-3 LDS
// bf16-packed, stripe 4 LDS bf16; ds_add_f32 col accumulation (R7: 1096 us, no spill).
// EARLY EXIT: w <- 1/(E^T (1/(E w))) is a fixed point iteration; for iid-random affinity the
// scaled matrix is an expander (sigma2 ~ 1/sqrt(315)) -> converges to fp precision in O(10)
// iters; iterations k..100 are then no-ops. Detect max_t |q_t * w_t - 1| < 1e-4 (rel w change)
// via LDS atomicMax (double-buffered slot), then run exactly ONE more full iteration (saves
// a, updates w — preserving "ends on col-norm") and break. If convergence is slow the flag
// never fires and we fall back to the full 100 iterations.
__global__ __launch_bounds__(512) void k_sinkhorn(float* __restrict__ sbuf,
                                                  const float* __restrict__ stats,
                                                  const float* __restrict__ gptr,
                                                  const float* __restrict__ bptr) {
  __shared__ unsigned Epk23[400 * 64];       // (stripe2, stripe3) bf16-packed   = 102400 B
  __shared__ unsigned short Eu4[400 * 64];   // stripe 4 bf16 (0 for pad cols)   =  51200 B
  __shared__ float wl[320];                  // col scaling w[t] (0 for t>=315)
  __shared__ float qsum[320];                // atomic col accumulator
  __shared__ float albuf[400];               // a[n] from the final row step
  __shared__ unsigned convs[2];              // double-buffered max-residual bits
  const int b = blockIdx.x;
  const int tid = threadIdx.x;
  const int wv = tid >> 6;           // 0..7
  const int l = tid & 63;
  float* S = sbuf + (size_t)b * NDIM * TPAD;
  const float NT = 400.0f * 315.0f;
  const float mean = stats[2 * b] / NT;
  const float var = stats[2 * b + 1] / NT - mean * mean;
  const float inv = rsqrtf(var + 1e-5f);
  const float gamma = gptr[0], beta = bptr[0];
  const float alpha = gamma * inv;
  const float L2E = 1.4426950408889634f;
  const float a2 = alpha * L2E;
  const float d2 = (beta - mean * alpha) * L2E;
  const int nbase = wv * 50;         // 50 rows per wave
  const float TOL = 1e-4f;

  unsigned E01[50];                  // (stripe0, stripe1) bf16-packed, registers
#pragma unroll
  for (int j = 0; j < 50; ++j) {
    const float* row = S + (size_t)(nbase + j) * TPAD;
    float e0 = __builtin_amdgcn_exp2f(fmaf(row[l], a2, d2));
    float e1 = __builtin_amdgcn_exp2f(fmaf(row[64 + l], a2, d2));
    float e2 = __builtin_amdgcn_exp2f(fmaf(row[128 + l], a2, d2));
    float e3 = __builtin_amdgcn_exp2f(fmaf(row[192 + l], a2, d2));
    E01[j] = pack2(e0, e1);
    Epk23[(nbase + j) * 64 + l] = pack2(e2, e3);
    float e4 = 0.0f;
    if (l < 59) e4 = __builtin_amdgcn_exp2f(fmaf(row[256 + l], a2, d2));
    Eu4[(nbase + j) * 64 + l] = (unsigned short)(rne_hi(e4) >> 16);
  }
  if (tid < 320) { wl[tid] = (tid < 315) ? 1.0f : 0.0f; qsum[tid] = 0.0f; }
  if (tid < 2) convs[tid] = 0u;
  __syncthreads();

  bool fin = false;
  for (int it = 0; it < NITER; ++it) {
    float w0 = wl[l], w1 = wl[64 + l], w2 = wl[128 + l], w3 = wl[192 + l], w4 = wl[256 + l];
    float q0 = 0.f, q1 = 0.f, q2 = 0.f, q3 = 0.f, q4 = 0.f;
#pragma unroll
    for (int jc = 0; jc < 10; ++jc) {
      float p[5], e2v[5], e3v[5], e4v[5];
#pragma unroll
      for (int u = 0; u < 5; ++u) {
        const int j = jc * 5 + u;
        unsigned v23 = Epk23[(nbase + j) * 64 + l];
        e2v[u] = unpk_lo(v23);
        e3v[u] = unpk_hi(v23);
        e4v[u] = __uint_as_float(((unsigned)Eu4[(nbase + j) * 64 + l]) << 16);
        float t = e4v[u] * w4;
        t = fmaf(e3v[u], w3, t);
        t = fmaf(e2v[u], w2, t);
        t = fmaf(unpk_hi(E01[j]), w1, t);
        p[u] = fmaf(unpk_lo(E01[j]), w0, t);
      }
      // 5 interleaved DPP reduction chains (ILP), results uniform in SGPRs
      float aj[5];
#pragma unroll
      for (int u = 0; u < 5; ++u) p[u] = dppadd<0x111, 0xf>(p[u]);
#pragma unroll
      for (int u = 0; u < 5; ++u) p[u] = dppadd<0x112, 0xf>(p[u]);
#pragma unroll
      for (int u = 0; u < 5; ++u) p[u] = dppadd<0x114, 0xf>(p[u]);
#pragma unroll
      for (int u = 0; u < 5; ++u) p[u] = dppadd<0x118, 0xf>(p[u]);
#pragma unroll
      for (int u = 0; u < 5; ++u) p[u] = dppadd<0x142, 0xa>(p[u]);
#pragma unroll
      for (int u = 0; u < 5; ++u) p[u] = dppadd<0x143, 0xc>(p[u]);
#pragma unroll
      for (int u = 0; u < 5; ++u) {
        float r = __builtin_amdgcn_rcpf(p[u]);
        aj[u] = __int_as_float(__builtin_amdgcn_readlane(__float_as_int(r), 63));
      }
#pragma unroll
      for (int u = 0; u < 5; ++u) {
        const int j = jc * 5 + u;
        q0 = fmaf(unpk_lo(E01[j]), aj[u], q0);
        q1 = fmaf(unpk_hi(E01[j]), aj[u], q1);
        q2 = fmaf(e2v[u], aj[u], q2);
        q3 = fmaf(e3v[u], aj[u], q3);
        q4 = fmaf(e4v[u], aj[u], q4);
      }
      if (fin && l == 0) {
#pragma unroll
        for (int u = 0; u < 5; ++u) albuf[nbase + jc * 5 + u] = aj[u];
      }
    }
    atomicAdd(&qsum[l], q0);
    atomicAdd(&qsum[64 + l], q1);
    atomicAdd(&qsum[128 + l], q2);
    atomicAdd(&qsum[192 + l], q3);
    atomicAdd(&qsum[256 + l], q4);
    __syncthreads();
    if (tid < 320) {
      float q = qsum[tid];
      if (tid < 315) {
        float r = fabsf(fmaf(q, wl[tid], -1.0f));  // |w_old/w_new - 1|
        atomicMax(&convs[it & 1], __float_as_uint(r));  // positive floats: uint order == float order
        wl[tid] = __builtin_amdgcn_rcpf(q);
      }
      qsum[tid] = 0.0f;  // re-zero for next iteration
    }
    __syncthreads();
    if (fin) break;
    float resid = __uint_as_float(convs[it & 1]);
    fin = (resid < TOL) || (it == NITER - 2);
    if (tid == 0) convs[(it + 1) & 1] = 0u;  // reset other slot (safe: next atomicMax is after next barrier)
  }

  // epilogue: s1 = a_fin * E * w_fin (a from albuf — NO extra row normalization)
  {
    float w0 = wl[l], w1 = wl[64 + l], w2 = wl[128 + l], w3 = wl[192 + l], w4 = wl[256 + l];
#pragma unroll
    for (int j = 0; j < 50; ++j) {
      const float aj = albuf[nbase + j];
      unsigned v23 = Epk23[(nbase + j) * 64 + l];
      float e4 = __uint_as_float(((unsigned)Eu4[(nbase + j) * 64 + l]) << 16);
      float* row = S + (size_t)(nbase + j) * TPAD;
      row[l] = aj * unpk_lo(E01[j]) * w0;
      row[64 + l] = aj * unpk_hi(E01[j]) * w1;
      row[128 + l] = aj * unpk_lo(v23) * w2;
      row[192 + l] = aj * unpk_hi(v23) * w3;
      if (l < 59) row[256 + l] = aj * e4 * w4;
    }
  }
}

// ---------------- K4: f1[b][t][d] = sum_n s1[b][n][t] * F[b][n][d]  (TN) ----------------
__global__ void k_f1(const float* __restrict__ s1, const float* __restrict__ F,
                     float* __restrict__ f1) {
  __shared__ float Xs[32 * 72], Ws[32 * 72];
  int tid = threadIdx.x, tm = tid >> 4, tn = tid & 15;
  int d0 = blockIdx.x * 64, t0 = blockIdx.y * 64, bz = blockIdx.z;
  const float* sb = s1 + (size_t)bz * NDIM * TPAD;
  const float* Fb = F + (size_t)bz * NDIM * DDIM;
  float* out = f1 + (size_t)bz * TDIM * DDIM;
  float acc[4][4] = {};
  for (int k0 = 0; k0 < 416; k0 += 32) {  // 13 chunks cover K=400 (masked)
    stage_N(Xs, sb, k0, TPAD, t0, tid, NDIM);
    stage_N(Ws, Fb, k0, DDIM, d0, tid, NDIM);
    __syncthreads();
    mm_inner(Xs, Ws, acc, tm, tn);
    __syncthreads();
  }
#pragma unroll
  for (int i = 0; i < 4; ++i) {
    int t = t0 + tm * 4 + i;
    if (t < TDIM)
      *(float4*)(out + (size_t)t * DDIM + d0 + tn * 4) =
          make_float4(acc[i][0], acc[i][1], acc[i][2], acc[i][3]);
  }
}

// ---------------- K5a: h[r][j] = relu(f1[r]. @ Wh_top + TB[r%315])  (NN) ----------------
__global__ void k_h(const float* __restrict__ f1, const float* __restrict__ Wh,
                    const float* __restrict__ TB, float* __restrict__ hbuf) {
  __shared__ float Xs[32 * 72], Ws[32 * 72];
  int tid = threadIdx.x, tm = tid >> 4, tn = tid & 15;
  int h0 = blockIdx.x * 64, r0 = blockIdx.y * 64;
  const int RTOT = BDIM * TDIM;  // 10080
  float acc[4][4] = {};
  for (int k0 = 0; k0 < 512; k0 += 32) {
    stage_T(Xs, f1, r0, 512, k0, tid, RTOT);
    stage_N(Ws, Wh, k0, 256, h0, tid, 512);
    __syncthreads();
    mm_inner(Xs, Ws, acc, tm, tn);
    __syncthreads();
  }
#pragma unroll
  for (int i = 0; i < 4; ++i) {
    int r = r0 + tm * 4 + i;
    if (r < RTOT) {
      int t = r % TDIM;
      int h = h0 + tn * 4;
      float4 v;
      v.x = fmaxf(acc[i][0] + TB[(size_t)t * 256 + h + 0], 0.f);
      v.y = fmaxf(acc[i][1] + TB[(size_t)t * 256 + h + 1], 0.f);
      v.z = fmaxf(acc[i][2] + TB[(size_t)t * 256 + h + 2], 0.f);
      v.w = fmaxf(acc[i][3] + TB[(size_t)t * 256 + h + 3], 0.f);
      *(float4*)(hbuf + (size_t)r * 256 + h) = v;
    }
  }
}

// ---------------- K5b: pred[r] = h[r]. @ Wo + bo ----------------
__global__ void k_pred(const float* __restrict__ hbuf, const float* __restrict__ Wo,
                       const float* __restrict__ bo, float* __restrict__ out) {
  int tid = threadIdx.x;
  int wv = tid >> 6, l = tid & 63;
  int r = blockIdx.x * 4 + wv;
  float s = 0.f;
#pragma unroll
  for (int k = 0; k < 4; ++k)
    s = fmaf(hbuf[(size_t)r * 256 + 64 * k + l], Wo[64 * k + l], s);
#pragma unroll
  for (int m = 1; m <= 32; m <<= 1) s += __shfl_xor(s, m, 64);
  if (l == 0) out[r] = s + bo[0];
}

// ---------------- launch ----------------
extern "C" void kernel_launch(void* const* d_in, const int* in_sizes, int n_in,
                              void* d_out, int out_size, void* d_ws, size_t ws_size,
                              hipStream_t stream) {
  const float* F     = (const float*)d_in[0];
  const float* text  = (const float*)d_in[1];
  const float* A     = (const float*)d_in[2];
  const float* gamma = (const float*)d_in[3];
  const float* beta  = (const float*)d_in[4];
  const float* Wh    = (const float*)d_in[5];
  const float* bh    = (const float*)d_in[6];
  const float* Wo    = (const float*)d_in[7];
  const float* bo    = (const float*)d_in[8];
  float* out = (float*)d_out;
  char* ws = (char*)d_ws;
  float* tA    = (float*)(ws + OFS_TA);
  float* TB    = (float*)(ws + OFS_TB);
  float* stats = (float*)(ws + OFS_STATS);
  float* sbuf  = (float*)(ws + OFS_S);
  float* f1    = (float*)(ws + OFS_F1);
  float* hbuf  = (float*)(ws + OFS_H);

  hipMemsetAsync(stats, 0, BDIM * 2 * sizeof(float), stream);
  k_tA<<<dim3(8, 5), 256, 0, stream>>>(text, A, tA);
  k_TB<<<dim3(4, 5), 256, 0, stream>>>(text, Wh, bh, TB);
  k_s<<<dim3(5, 7, 32), 256, 0, stream>>>(F, tA, sbuf, stats);
  k_sinkhorn<<<dim3(32), 512, 0, stream>>>(sbuf, stats, gamma, beta);
  k_f1<<<dim3(8, 5, 32), 256, 0, stream>>>(sbuf, F, f1);
  k_h<<<dim3(4, 158), 256, 0, stream>>>(f1, Wh, TB, hbuf);
  k_pred<<<dim3(2520), 256, 0, stream>>>(hbuf, Wo, bo, out);
}

// Round 9
// 484.944 us; speedup vs baseline: 3.3536x; 3.3536x over previous
//
#include <hip/hip_runtime.h>

// Problem dims
#define BDIM 32
#define NDIM 400
#define TDIM 315
#define TPAD 320
#define DDIM 512
#define HDIM 256
#define NITER 100

// Workspace layout (bytes)
#define OFS_TA    0u          // tA[320][512] f32 = 655360
#define OFS_TB    1048576u    // TB[320][256] f32 = 327680   (text @ Wh_bot + bh)
#define OFS_STATS 1572864u    // stats[32][2] f32 = 256      (sum, sumsq per batch)
#define OFS_S     2097152u    // s/s1[32][400][320] f32 = 16384000
#define OFS_F1    18874368u   // f1[32][315][512] f32 = 20643840
#define OFS_H     41943040u   // h[10080][256] f32 = 10321920

// ---------------- shared GEMM pieces: 64x64 tile, BK=32, 256 thr, 4x4 micro ----------------

__device__ __forceinline__ void mm_inner(const float* __restrict__ As, const float* __restrict__ Bs,
                                         float acc[4][4], int tm, int tn) {
#pragma unroll
  for (int k = 0; k < 32; ++k) {
    float4 a = *(const float4*)(As + k * 72 + tm * 4);
    float4 b = *(const float4*)(Bs + k * 72 + tn * 4);
    float ar[4] = {a.x, a.y, a.z, a.w};
    float br[4] = {b.x, b.y, b.z, b.w};
#pragma unroll
    for (int i = 0; i < 4; ++i)
#pragma unroll
      for (int j = 0; j < 4; ++j)
        acc[i][j] = fmaf(ar[i], br[j], acc[i][j]);
  }
}

// Stage X[row][k] (K-contiguous rows) transposed into Xs[k][m]; rows >= rmax -> 0
__device__ __forceinline__ void stage_T(float* __restrict__ Xs, const float* __restrict__ X,
                                        int r0, int ld, int k0, int tid, int rmax) {
  int kq = tid & 7;   // float4 group along K
  int mb = tid >> 3;  // 0..31
#pragma unroll
  for (int p = 0; p < 2; ++p) {
    int mm = mb + 32 * p;
    int row = r0 + mm;
    float4 v = make_float4(0.f, 0.f, 0.f, 0.f);
    if (row < rmax) v = *(const float4*)(X + (size_t)row * ld + k0 + 4 * kq);
    Xs[(4 * kq + 0) * 72 + mm] = v.x;
    Xs[(4 * kq + 1) * 72 + mm] = v.y;
    Xs[(4 * kq + 2) * 72 + mm] = v.z;
    Xs[(4 * kq + 3) * 72 + mm] = v.w;
  }
}

// Stage W[k][n] (N-contiguous rows) into Ws[k][j]; k0+k >= kmax -> 0
__device__ __forceinline__ void stage_N(float* __restrict__ Ws, const float* __restrict__ W,
                                        int k0, int ld, int n0, int tid, int kmax) {
  int nq = tid & 15;
  int kk = tid >> 4;  // 0..15
#pragma unroll
  for (int p = 0; p < 2; ++p) {
    int k = kk + 16 * p;
    float4 v = make_float4(0.f, 0.f, 0.f, 0.f);
    if (k0 + k < kmax) v = *(const float4*)(W + (size_t)(k0 + k) * ld + n0 + 4 * nq);
    *(float4*)(Ws + k * 72 + 4 * nq) = v;
  }
}

// ---------------- K1a: tA[t][d] = sum_e text[t][e] * A[d][e]  (NT) ----------------
__global__ void k_tA(const float* __restrict__ text, const float* __restrict__ A,
                     float* __restrict__ tA) {
  __shared__ float Xs[32 * 72], Ys[32 * 72];
  int tid = threadIdx.x, tm = tid >> 4, tn = tid & 15;
  int d0 = blockIdx.x * 64, t0 = blockIdx.y * 64;
  float acc[4][4] = {};
  for (int k0 = 0; k0 < 512; k0 += 32) {
    stage_T(Xs, text, t0, 512, k0, tid, TDIM);
    stage_T(Ys, A, d0, 512, k0, tid, 512);
    __syncthreads();
    mm_inner(Xs, Ys, acc, tm, tn);
    __syncthreads();
  }
#pragma unroll
  for (int i = 0; i < 4; ++i) {
    int t = t0 + tm * 4 + i;  // pad rows get zeros (Xs zero-filled)
    *(float4*)(tA + (size_t)t * 512 + d0 + tn * 4) =
        make_float4(acc[i][0], acc[i][1], acc[i][2], acc[i][3]);
  }
}

// ---------------- K1b: TB[t][h] = text[t]. @ Wh_bot + bh  (NN) ----------------
__global__ void k_TB(const float* __restrict__ text, const float* __restrict__ Wh,
                     const float* __restrict__ bh, float* __restrict__ TB) {
  __shared__ float Xs[32 * 72], Ws[32 * 72];
  int tid = threadIdx.x, tm = tid >> 4, tn = tid & 15;
  int h0 = blockIdx.x * 64, t0 = blockIdx.y * 64;
  const float* Wb = Wh + 512 * 256;  // bottom half rows of Wh[1024][256]
  float acc[4][4] = {};
  for (int k0 = 0; k0 < 512; k0 += 32) {
    stage_T(Xs, text, t0, 512, k0, tid, TDIM);
    stage_N(Ws, Wb, k0, 256, h0, tid, 512);
    __syncthreads();
    mm_inner(Xs, Ws, acc, tm, tn);
    __syncthreads();
  }
#pragma unroll
  for (int i = 0; i < 4; ++i) {
    int t = t0 + tm * 4 + i;
    int h = h0 + tn * 4;
    *(float4*)(TB + (size_t)t * 256 + h) =
        make_float4(acc[i][0] + bh[h], acc[i][1] + bh[h + 1],
                    acc[i][2] + bh[h + 2], acc[i][3] + bh[h + 3]);
  }
}

// ---------------- K2: s[b][n][t] = F[b][n]. dot tA[t].  (NT) + instnorm stats ----------------
__global__ void k_s(const float* __restrict__ F, const float* __restrict__ tA,
                    float* __restrict__ s, float* __restrict__ stats) {
  __shared__ float Xs[32 * 72], Ys[32 * 72];
  __shared__ float red[8];
  int tid = threadIdx.x, tm = tid >> 4, tn = tid & 15;
  int t0 = blockIdx.x * 64, n0 = blockIdx.y * 64, bz = blockIdx.z;
  const float* Fb = F + (size_t)bz * NDIM * DDIM;
  float* sb = s + (size_t)bz * NDIM * TPAD;
  float acc[4][4] = {};
  for (int k0 = 0; k0 < 512; k0 += 32) {
    stage_T(Xs, Fb, n0, 512, k0, tid, NDIM);
    stage_T(Ys, tA, t0, 512, k0, tid, TPAD);  // pad rows of tA are zeros
    __syncthreads();
    mm_inner(Xs, Ys, acc, tm, tn);
    __syncthreads();
  }
  float lsum = 0.f, lsq = 0.f;
#pragma unroll
  for (int i = 0; i < 4; ++i) {
    int n = n0 + tm * 4 + i;
    if (n < NDIM) {
      int tb = t0 + tn * 4;
      if (tb + 3 < TDIM) {
        *(float4*)(sb + (size_t)n * TPAD + tb) =
            make_float4(acc[i][0], acc[i][1], acc[i][2], acc[i][3]);
#pragma unroll
        for (int j = 0; j < 4; ++j) { lsum += acc[i][j]; lsq = fmaf(acc[i][j], acc[i][j], lsq); }
      } else {
#pragma unroll
        for (int j = 0; j < 4; ++j) {
          int t = tb + j;
          if (t < TDIM) {
            sb[(size_t)n * TPAD + t] = acc[i][j];
            lsum += acc[i][j]; lsq = fmaf(acc[i][j], acc[i][j], lsq);
          }
        }
      }
    }
  }
#pragma unroll
  for (int m = 1; m <= 32; m <<= 1) {
    lsum += __shfl_xor(lsum, m, 64);
    lsq  += __shfl_xor(lsq, m, 64);
  }
  int wv = tid >> 6;
  if ((tid & 63) == 0) { red[wv * 2] = lsum; red[wv * 2 + 1] = lsq; }
  __syncthreads();
  if (tid == 0) {
    float S = red[0] + red[2] + red[4] + red[6];
    float Q = red[1] + red[3] + red[5] + red[7];
    atomicAdd(&stats[bz * 2], S);
    atomicAdd(&stats[bz * 2 + 1], Q);
  }
}

// ---------------- DPP wave-64 reduce helpers (VALU pipe, no LDS) ----------------
template <int CTRL, int RMASK>
__device__ __forceinline__ float dppadd(float x) {
  int y = __builtin_amdgcn_update_dpp(0, __float_as_int(x), CTRL, RMASK, 0xf, true);
  return x + __int_as_float(y);
}
template <int CTRL, int RMASK>
__device__ __forceinline__ float dppmax(float x) {
  int y = __builtin_amdgcn_update_dpp(0, __float_as_int(x), CTRL, RMASK, 0xf, true);
  return fmaxf(x, __int_as_float(y));
}

// ---------------- bf16 pack/unpack (RNE) ----------------
__device__ __forceinline__ unsigned rne_hi(float x) {
  unsigned u = __float_as_uint(x);
  u += 0x7fffu + ((u >> 16) & 1u);
  return u & 0xffff0000u;
}
__device__ __forceinline__ unsigned pack2(float lo, float hi) {
  return (rne_hi(lo) >> 16) | rne_hi(hi);
}
__device__ __forceinline__ float unpk_lo(unsigned p) { return __uint_as_float(p << 16); }
__device__ __forceinline__ float unpk_hi(unsigned p) { return __uint_as_float(p & 0xffff0000u); }

// ---------------- K3: fused instnorm finalize + sinkhorn (matrix scaling, early-exit) ----------
// 512 threads (8 waves). E stripes 0-1 in registers (50 bf16-packed uints), stripes 2-3 LDS
// bf16-packed, stripe 4 LDS bf16; ds_add_f32 col accumulation (R7: 1096 us, no spill).
// EARLY EXIT (R8 post-mortem): with N=400 != T=315 the marginals are inconsistent, so w converges
// in DIRECTION only, scaling by a constant factor each iteration; at the fixed direction the
// row-normalized matrix has uniform col sums = N/T = 400/315. R8's |q*w - 1| -> 0.27 never fired.
// Corrected residual: r = |q*w*(T/N) - 1| -> 0. Wave-level DPP max + ONE atomicMax per wave
// (R8's 315-way single-address contention cost ~1.9 us/iter). On trigger, run exactly one more
// full iteration (saves a, updates w — preserving "ends on col-norm") and break. Fallback: 100.
__global__ __launch_bounds__(512) void k_sinkhorn(float* __restrict__ sbuf,
                                                  const float* __restrict__ stats,
                                                  const float* __restrict__ gptr,
                                                  const float* __restrict__ bptr) {
  __shared__ unsigned Epk23[400 * 64];       // (stripe2, stripe3) bf16-packed   = 102400 B
  __shared__ unsigned short Eu4[400 * 64];   // stripe 4 bf16 (0 for pad cols)   =  51200 B
  __shared__ float wl[320];                  // col scaling w[t] (0 for t>=315)
  __shared__ float qsum[320];                // atomic col accumulator
  __shared__ float albuf[400];               // a[n] from the final row step
  __shared__ unsigned convs[2];              // double-buffered max-residual bits
  const int b = blockIdx.x;
  const int tid = threadIdx.x;
  const int wv = tid >> 6;           // 0..7
  const int l = tid & 63;
  float* S = sbuf + (size_t)b * NDIM * TPAD;
  const float NT = 400.0f * 315.0f;
  const float mean = stats[2 * b] / NT;
  const float var = stats[2 * b + 1] / NT - mean * mean;
  const float inv = rsqrtf(var + 1e-5f);
  const float gamma = gptr[0], beta = bptr[0];
  const float alpha = gamma * inv;
  const float L2E = 1.4426950408889634f;
  const float a2 = alpha * L2E;
  const float d2 = (beta - mean * alpha) * L2E;
  const int nbase = wv * 50;         // 50 rows per wave
  const float TOL = 1e-4f;
  const float TN_RATIO = 315.0f / 400.0f;  // q*w converges to N/T; scale to 1

  unsigned E01[50];                  // (stripe0, stripe1) bf16-packed, registers
#pragma unroll
  for (int j = 0; j < 50; ++j) {
    const float* row = S + (size_t)(nbase + j) * TPAD;
    float e0 = __builtin_amdgcn_exp2f(fmaf(row[l], a2, d2));
    float e1 = __builtin_amdgcn_exp2f(fmaf(row[64 + l], a2, d2));
    float e2 = __builtin_amdgcn_exp2f(fmaf(row[128 + l], a2, d2));
    float e3 = __builtin_amdgcn_exp2f(fmaf(row[192 + l], a2, d2));
    E01[j] = pack2(e0, e1);
    Epk23[(nbase + j) * 64 + l] = pack2(e2, e3);
    float e4 = 0.0f;
    if (l < 59) e4 = __builtin_amdgcn_exp2f(fmaf(row[256 + l], a2, d2));
    Eu4[(nbase + j) * 64 + l] = (unsigned short)(rne_hi(e4) >> 16);
  }
  if (tid < 320) { wl[tid] = (tid < 315) ? 1.0f : 0.0f; qsum[tid] = 0.0f; }
  if (tid < 2) convs[tid] = 0u;
  __syncthreads();

  bool fin = false;
  for (int it = 0; it < NITER; ++it) {
    float w0 = wl[l], w1 = wl[64 + l], w2 = wl[128 + l], w3 = wl[192 + l], w4 = wl[256 + l];
    float q0 = 0.f, q1 = 0.f, q2 = 0.f, q3 = 0.f, q4 = 0.f;
#pragma unroll
    for (int jc = 0; jc < 10; ++jc) {
      float p[5], e2v[5], e3v[5], e4v[5];
#pragma unroll
      for (int u = 0; u < 5; ++u) {
        const int j = jc * 5 + u;
        unsigned v23 = Epk23[(nbase + j) * 64 + l];
        e2v[u] = unpk_lo(v23);
        e3v[u] = unpk_hi(v23);
        e4v[u] = __uint_as_float(((unsigned)Eu4[(nbase + j) * 64 + l]) << 16);
        float t = e4v[u] * w4;
        t = fmaf(e3v[u], w3, t);
        t = fmaf(e2v[u], w2, t);
        t = fmaf(unpk_hi(E01[j]), w1, t);
        p[u] = fmaf(unpk_lo(E01[j]), w0, t);
      }
      // 5 interleaved DPP reduction chains (ILP), results uniform in SGPRs
      float aj[5];
#pragma unroll
      for (int u = 0; u < 5; ++u) p[u] = dppadd<0x111, 0xf>(p[u]);
#pragma unroll
      for (int u = 0; u < 5; ++u) p[u] = dppadd<0x112, 0xf>(p[u]);
#pragma unroll
      for (int u = 0; u < 5; ++u) p[u] = dppadd<0x114, 0xf>(p[u]);
#pragma unroll
      for (int u = 0; u < 5; ++u) p[u] = dppadd<0x118, 0xf>(p[u]);
#pragma unroll
      for (int u = 0; u < 5; ++u) p[u] = dppadd<0x142, 0xa>(p[u]);
#pragma unroll
      for (int u = 0; u < 5; ++u) p[u] = dppadd<0x143, 0xc>(p[u]);
#pragma unroll
      for (int u = 0; u < 5; ++u) {
        float r = __builtin_amdgcn_rcpf(p[u]);
        aj[u] = __int_as_float(__builtin_amdgcn_readlane(__float_as_int(r), 63));
      }
#pragma unroll
      for (int u = 0; u < 5; ++u) {
        const int j = jc * 5 + u;
        q0 = fmaf(unpk_lo(E01[j]), aj[u], q0);
        q1 = fmaf(unpk_hi(E01[j]), aj[u], q1);
        q2 = fmaf(e2v[u], aj[u], q2);
        q3 = fmaf(e3v[u], aj[u], q3);
        q4 = fmaf(e4v[u], aj[u], q4);
      }
      if (fin && l == 0) {
#pragma unroll
        for (int u = 0; u < 5; ++u) albuf[nbase + jc * 5 + u] = aj[u];
      }
    }
    atomicAdd(&qsum[l], q0);
    atomicAdd(&qsum[64 + l], q1);
    atomicAdd(&qsum[128 + l], q2);
    atomicAdd(&qsum[192 + l], q3);
    atomicAdd(&qsum[256 + l], q4);
    __syncthreads();
    if (tid < 320) {  // exactly 5 full waves
      float q = qsum[tid];
      float r = 0.0f;
      if (tid < 315) {
        r = fabsf(fmaf(q * wl[tid], TN_RATIO, -1.0f));  // |q*w_old*(T/N) - 1| -> 0
        wl[tid] = __builtin_amdgcn_rcpf(q);
      }
      qsum[tid] = 0.0f;  // re-zero for next iteration
      // wave-level max then one atomic per wave (contention 5, not 315)
      r = dppmax<0x111, 0xf>(r);
      r = dppmax<0x112, 0xf>(r);
      r = dppmax<0x114, 0xf>(r);
      r = dppmax<0x118, 0xf>(r);
      r = dppmax<0x142, 0xa>(r);
      r = dppmax<0x143, 0xc>(r);
      if (l == 63) atomicMax(&convs[it & 1], __float_as_uint(r));
    }
    __syncthreads();
    if (fin) break;
    float resid = __uint_as_float(convs[it & 1]);
    fin = (resid < TOL) || (it == NITER - 2);
    if (tid == 0) convs[(it + 1) & 1] = 0u;  // reset other slot (safe: next atomicMax after next barrier)
  }

  // epilogue: s1 = a_fin * E * w_fin (a from albuf — NO extra row normalization)
  {
    float w0 = wl[l], w1 = wl[64 + l], w2 = wl[128 + l], w3 = wl[192 + l], w4 = wl[256 + l];
#pragma unroll
    for (int j = 0; j < 50; ++j) {
      const float aj = albuf[nbase + j];
      unsigned v23 = Epk23[(nbase + j) * 64 + l];
      float e4 = __uint_as_float(((unsigned)Eu4[(nbase + j) * 64 + l]) << 16);
      float* row = S + (size_t)(nbase + j) * TPAD;
      row[l] = aj * unpk_lo(E01[j]) * w0;
      row[64 + l] = aj * unpk_hi(E01[j]) * w1;
      row[128 + l] = aj * unpk_lo(v23) * w2;
      row[192 + l] = aj * unpk_hi(v23) * w3;
      if (l < 59) row[256 + l] = aj * e4 * w4;
    }
  }
}

// ---------------- K4: f1[b][t][d] = sum_n s1[b][n][t] * F[b][n][d]  (TN) ----------------
__global__ void k_f1(const float* __restrict__ s1, const float* __restrict__ F,
                     float* __restrict__ f1) {
  __shared__ float Xs[32 * 72], Ws[32 * 72];
  int tid = threadIdx.x, tm = tid >> 4, tn = tid & 15;
  int d0 = blockIdx.x * 64, t0 = blockIdx.y * 64, bz = blockIdx.z;
  const float* sb = s1 + (size_t)bz * NDIM * TPAD;
  const float* Fb = F + (size_t)bz * NDIM * DDIM;
  float* out = f1 + (size_t)bz * TDIM * DDIM;
  float acc[4][4] = {};
  for (int k0 = 0; k0 < 416; k0 += 32) {  // 13 chunks cover K=400 (masked)
    stage_N(Xs, sb, k0, TPAD, t0, tid, NDIM);
    stage_N(Ws, Fb, k0, DDIM, d0, tid, NDIM);
    __syncthreads();
    mm_inner(Xs, Ws, acc, tm, tn);
    __syncthreads();
  }
#pragma unroll
  for (int i = 0; i < 4; ++i) {
    int t = t0 + tm * 4 + i;
    if (t < TDIM)
      *(float4*)(out + (size_t)t * DDIM + d0 + tn * 4) =
          make_float4(acc[i][0], acc[i][1], acc[i][2], acc[i][3]);
  }
}

// ---------------- K5a: h[r][j] = relu(f1[r]. @ Wh_top + TB[r%315])  (NN) ----------------
__global__ void k_h(const float* __restrict__ f1, const float* __restrict__ Wh,
                    const float* __restrict__ TB, float* __restrict__ hbuf) {
  __shared__ float Xs[32 * 72], Ws[32 * 72];
  int tid = threadIdx.x, tm = tid >> 4, tn = tid & 15;
  int h0 = blockIdx.x * 64, r0 = blockIdx.y * 64;
  const int RTOT = BDIM * TDIM;  // 10080
  float acc[4][4] = {};
  for (int k0 = 0; k0 < 512; k0 += 32) {
    stage_T(Xs, f1, r0, 512, k0, tid, RTOT);
    stage_N(Ws, Wh, k0, 256, h0, tid, 512);
    __syncthreads();
    mm_inner(Xs, Ws, acc, tm, tn);
    __syncthreads();
  }
#pragma unroll
  for (int i = 0; i < 4; ++i) {
    int r = r0 + tm * 4 + i;
    if (r < RTOT) {
      int t = r % TDIM;
      int h = h0 + tn * 4;
      float4 v;
      v.x = fmaxf(acc[i][0] + TB[(size_t)t * 256 + h + 0], 0.f);
      v.y = fmaxf(acc[i][1] + TB[(size_t)t * 256 + h + 1], 0.f);
      v.z = fmaxf(acc[i][2] + TB[(size_t)t * 256 + h + 2], 0.f);
      v.w = fmaxf(acc[i][3] + TB[(size_t)t * 256 + h + 3], 0.f);
      *(float4*)(hbuf + (size_t)r * 256 + h) = v;
    }
  }
}

// ---------------- K5b: pred[r] = h[r]. @ Wo + bo ----------------
__global__ void k_pred(const float* __restrict__ hbuf, const float* __restrict__ Wo,
                       const float* __restrict__ bo, float* __restrict__ out) {
  int tid = threadIdx.x;
  int wv = tid >> 6, l = tid & 63;
  int r = blockIdx.x * 4 + wv;
  float s = 0.f;
#pragma unroll
  for (int k = 0; k < 4; ++k)
    s = fmaf(hbuf[(size_t)r * 256 + 64 * k + l], Wo[64 * k + l], s);
#pragma unroll
  for (int m = 1; m <= 32; m <<= 1) s += __shfl_xor(s, m, 64);
  if (l == 0) out[r] = s + bo[0];
}

// ---------------- launch ----------------
extern "C" void kernel_launch(void* const* d_in, const int* in_sizes, int n_in,
                              void* d_out, int out_size, void* d_ws, size_t ws_size,
                              hipStream_t stream) {
  const float* F     = (const float*)d_in[0];
  const float* text  = (const float*)d_in[1];
  const float* A     = (const float*)d_in[2];
  const float* gamma = (const float*)d_in[3];
  const float* beta  = (const float*)d_in[4];
  const float* Wh    = (const float*)d_in[5];
  const float* bh    = (const float*)d_in[6];
  const float* Wo    = (const float*)d_in[7];
  const float* bo    = (const float*)d_in[8];
  float* out = (float*)d_out;
  char* ws = (char*)d_ws;
  float* tA    = (float*)(ws + OFS_TA);
  float* TB    = (float*)(ws + OFS_TB);
  float* stats = (float*)(ws + OFS_STATS);
  float* sbuf  = (float*)(ws + OFS_S);
  float* f1    = (float*)(ws + OFS_F1);
  float* hbuf  = (float*)(ws + OFS_H);

  hipMemsetAsync(stats, 0, BDIM * 2 * sizeof(float), stream);
  k_tA<<<dim3(8, 5), 256, 0, stream>>>(text, A, tA);
  k_TB<<<dim3(4, 5), 256, 0, stream>>>(text, Wh, bh, TB);
  k_s<<<dim3(5, 7, 32), 256, 0, stream>>>(F, tA, sbuf, stats);
  k_sinkhorn<<<dim3(32), 512, 0, stream>>>(sbuf, stats, gamma, beta);
  k_f1<<<dim3(8, 5, 32), 256, 0, stream>>>(sbuf, F, f1);
  k_h<<<dim3(4, 158), 256, 0, stream>>>(f1, Wh, TB, hbuf);
  k_pred<<<dim3(2520), 256, 0, stream>>>(hbuf, Wo, bo, out);
}

// Round 10
// 373.045 us; speedup vs baseline: 4.3595x; 1.3000x over previous
//
#include <hip/hip_runtime.h>

// Problem dims
#define BDIM 32
#define NDIM 400
#define TDIM 315
#define TPAD 320
#define DDIM 512
#define HDIM 256
#define NITER 100

// Workspace layout (bytes)
#define OFS_TA    0u          // tA[320][512] f32 = 655360
#define OFS_TB    1048576u    // TB[320][256] f32 = 327680   (text @ Wh_bot + bh)
#define OFS_STATS 1572864u    // stats[32][2] f32 = 256      (sum, sumsq per batch)
#define OFS_S     2097152u    // s/s1[32][400][320] f32 = 16384000
#define OFS_F1    18874368u   // f1[32][315][512] f32 = 20643840
#define OFS_H     41943040u   // h[10080][256] f32 = 10321920

typedef __attribute__((ext_vector_type(8))) short bf16x8;
typedef __attribute__((ext_vector_type(4))) float f32x4;

// ---------------- bf16 pack/unpack (RNE) ----------------
__device__ __forceinline__ unsigned rne_hi(float x) {
  unsigned u = __float_as_uint(x);
  u += 0x7fffu + ((u >> 16) & 1u);
  return u & 0xffff0000u;
}
__device__ __forceinline__ unsigned pack2(float lo, float hi) {
  return (rne_hi(lo) >> 16) | rne_hi(hi);
}
__device__ __forceinline__ unsigned short bf1(float x) { return (unsigned short)(rne_hi(x) >> 16); }
__device__ __forceinline__ float unpk_lo(unsigned p) { return __uint_as_float(p << 16); }
__device__ __forceinline__ float unpk_hi(unsigned p) { return __uint_as_float(p & 0xffff0000u); }

// ---------------- fp32 GEMM pieces (still used by small k_tA / k_TB) ----------------
__device__ __forceinline__ void mm_inner(const float* __restrict__ As, const float* __restrict__ Bs,
                                         float acc[4][4], int tm, int tn) {
#pragma unroll
  for (int k = 0; k < 32; ++k) {
    float4 a = *(const float4*)(As + k * 72 + tm * 4);
    float4 b = *(const float4*)(Bs + k * 72 + tn * 4);
    float ar[4] = {a.x, a.y, a.z, a.w};
    float br[4] = {b.x, b.y, b.z, b.w};
#pragma unroll
    for (int i = 0; i < 4; ++i)
#pragma unroll
      for (int j = 0; j < 4; ++j)
        acc[i][j] = fmaf(ar[i], br[j], acc[i][j]);
  }
}

__device__ __forceinline__ void stage_T(float* __restrict__ Xs, const float* __restrict__ X,
                                        int r0, int ld, int k0, int tid, int rmax) {
  int kq = tid & 7;
  int mb = tid >> 3;
#pragma unroll
  for (int p = 0; p < 2; ++p) {
    int mm = mb + 32 * p;
    int row = r0 + mm;
    float4 v = make_float4(0.f, 0.f, 0.f, 0.f);
    if (row < rmax) v = *(const float4*)(X + (size_t)row * ld + k0 + 4 * kq);
    Xs[(4 * kq + 0) * 72 + mm] = v.x;
    Xs[(4 * kq + 1) * 72 + mm] = v.y;
    Xs[(4 * kq + 2) * 72 + mm] = v.z;
    Xs[(4 * kq + 3) * 72 + mm] = v.w;
  }
}

__device__ __forceinline__ void stage_N(float* __restrict__ Ws, const float* __restrict__ W,
                                        int k0, int ld, int n0, int tid, int kmax) {
  int nq = tid & 15;
  int kk = tid >> 4;
#pragma unroll
  for (int p = 0; p < 2; ++p) {
    int k = kk + 16 * p;
    float4 v = make_float4(0.f, 0.f, 0.f, 0.f);
    if (k0 + k < kmax) v = *(const float4*)(W + (size_t)(k0 + k) * ld + n0 + 4 * nq);
    *(float4*)(Ws + k * 72 + 4 * nq) = v;
  }
}

// ---------------- K1a: tA[t][d] = sum_e text[t][e] * A[d][e]  (NT, fp32 — small) -------------
__global__ void k_tA(const float* __restrict__ text, const float* __restrict__ A,
                     float* __restrict__ tA) {
  __shared__ float Xs[32 * 72], Ys[32 * 72];
  int tid = threadIdx.x, tm = tid >> 4, tn = tid & 15;
  int d0 = blockIdx.x * 64, t0 = blockIdx.y * 64;
  float acc[4][4] = {};
  for (int k0 = 0; k0 < 512; k0 += 32) {
    stage_T(Xs, text, t0, 512, k0, tid, TDIM);
    stage_T(Ys, A, d0, 512, k0, tid, 512);
    __syncthreads();
    mm_inner(Xs, Ys, acc, tm, tn);
    __syncthreads();
  }
#pragma unroll
  for (int i = 0; i < 4; ++i) {
    int t = t0 + tm * 4 + i;  // pad rows get zeros (Xs zero-filled)
    *(float4*)(tA + (size_t)t * 512 + d0 + tn * 4) =
        make_float4(acc[i][0], acc[i][1], acc[i][2], acc[i][3]);
  }
}

// ---------------- K1b: TB[t][h] = text[t]. @ Wh_bot + bh  (NN, fp32 — small) ----------------
__global__ void k_TB(const float* __restrict__ text, const float* __restrict__ Wh,
                     const float* __restrict__ bh, float* __restrict__ TB) {
  __shared__ float Xs[32 * 72], Ws[32 * 72];
  int tid = threadIdx.x, tm = tid >> 4, tn = tid & 15;
  int h0 = blockIdx.x * 64, t0 = blockIdx.y * 64;
  const float* Wb = Wh + 512 * 256;
  float acc[4][4] = {};
  for (int k0 = 0; k0 < 512; k0 += 32) {
    stage_T(Xs, text, t0, 512, k0, tid, TDIM);
    stage_N(Ws, Wb, k0, 256, h0, tid, 512);
    __syncthreads();
    mm_inner(Xs, Ws, acc, tm, tn);
    __syncthreads();
  }
#pragma unroll
  for (int i = 0; i < 4; ++i) {
    int t = t0 + tm * 4 + i;
    int h = h0 + tn * 4;
    *(float4*)(TB + (size_t)t * 256 + h) =
        make_float4(acc[i][0] + bh[h], acc[i][1] + bh[h + 1],
                    acc[i][2] + bh[h + 2], acc[i][3] + bh[h + 3]);
  }
}

// ================= MFMA GEMMs: 64x64 tile, 256 thr (4 waves), 16x16x32 bf16 =================
// LDS operand layout [dim][k]: row stride 40 halves (80 B, 16B-aligned, <=2-way banks).
// A-frag: m=lane&15, k=(lane>>4)*8+j  (one ds_read_b128). B-frag symmetric (n=lane&15).
// D: col(lane&15)=B-dim, row((lane>>4)*4+reg)=A-dim  [verified mappings, guide §3].
#define LDH 40

// ---------------- K2: s[b][n][t] = F[b][n]. dot tA[t].  (NT bf16 MFMA) + instnorm stats -----
__global__ __launch_bounds__(256) void k_s(const float* __restrict__ F,
                                           const float* __restrict__ tA,
                                           float* __restrict__ s, float* __restrict__ stats) {
  __shared__ unsigned short Abf[64 * LDH];
  __shared__ unsigned short Bbf[64 * LDH];
  __shared__ float red[8];
  const int tid = threadIdx.x, l = tid & 63, wv = tid >> 6;
  const int t0 = blockIdx.x * 64, n0 = blockIdx.y * 64, bz = blockIdx.z;
  const float* Fb = F + (size_t)bz * NDIM * DDIM;
  float* sb = s + (size_t)bz * NDIM * TPAD;
  f32x4 acc[4] = {};
  const int m = tid >> 2, kq = (tid & 3) * 8;  // staging coords
  for (int k0 = 0; k0 < 512; k0 += 32) {
    // stage A (F rows, K-contiguous), mask n>=400 -> 0
    float4 v0 = make_float4(0.f, 0.f, 0.f, 0.f), v1 = v0;
    int n = n0 + m;
    if (n < NDIM) {
      v0 = *(const float4*)(Fb + (size_t)n * DDIM + k0 + kq);
      v1 = *(const float4*)(Fb + (size_t)n * DDIM + k0 + kq + 4);
    }
    unsigned pa[4] = {pack2(v0.x, v0.y), pack2(v0.z, v0.w), pack2(v1.x, v1.y), pack2(v1.z, v1.w)};
    *(uint4*)(&Abf[m * LDH + kq]) = make_uint4(pa[0], pa[1], pa[2], pa[3]);
    // stage B (tA rows, K-contiguous); rows 315..319 are zeros by k_tA
    float4 w0 = *(const float4*)(tA + (size_t)(t0 + m) * DDIM + k0 + kq);
    float4 w1 = *(const float4*)(tA + (size_t)(t0 + m) * DDIM + k0 + kq + 4);
    unsigned pb[4] = {pack2(w0.x, w0.y), pack2(w0.z, w0.w), pack2(w1.x, w1.y), pack2(w1.z, w1.w)};
    *(uint4*)(&Bbf[m * LDH + kq]) = make_uint4(pb[0], pb[1], pb[2], pb[3]);
    __syncthreads();
    bf16x8 af = *(const bf16x8*)(&Abf[(wv * 16 + (l & 15)) * LDH + (l >> 4) * 8]);
#pragma unroll
    for (int c = 0; c < 4; ++c) {
      bf16x8 bf_ = *(const bf16x8*)(&Bbf[(c * 16 + (l & 15)) * LDH + (l >> 4) * 8]);
      acc[c] = __builtin_amdgcn_mfma_f32_16x16x32_bf16(af, bf_, acc[c], 0, 0, 0);
    }
    __syncthreads();
  }
  float lsum = 0.f, lsq = 0.f;
#pragma unroll
  for (int c = 0; c < 4; ++c)
#pragma unroll
    for (int r = 0; r < 4; ++r) {
      int n = n0 + wv * 16 + ((l >> 4) << 2) + r;
      int t = t0 + c * 16 + (l & 15);
      if (n < NDIM && t < TDIM) {
        float v = acc[c][r];
        sb[(size_t)n * TPAD + t] = v;
        lsum += v;
        lsq = fmaf(v, v, lsq);
      }
    }
#pragma unroll
  for (int mm = 1; mm <= 32; mm <<= 1) {
    lsum += __shfl_xor(lsum, mm, 64);
    lsq += __shfl_xor(lsq, mm, 64);
  }
  if ((tid & 63) == 0) { red[wv * 2] = lsum; red[wv * 2 + 1] = lsq; }
  __syncthreads();
  if (tid == 0) {
    float S = red[0] + red[2] + red[4] + red[6];
    float Q = red[1] + red[3] + red[5] + red[7];
    atomicAdd(&stats[bz * 2], S);
    atomicAdd(&stats[bz * 2 + 1], Q);
  }
}

// ---------------- DPP wave-64 reduce helpers (VALU pipe, no LDS) ----------------
template <int CTRL, int RMASK>
__device__ __forceinline__ float dppadd(float x) {
  int y = __builtin_amdgcn_update_dpp(0, __float_as_int(x), CTRL, RMASK, 0xf, true);
  return x + __int_as_float(y);
}
template <int CTRL, int RMASK>
__device__ __forceinline__ float dppmax(float x) {
  int y = __builtin_amdgcn_update_dpp(0, __float_as_int(x), CTRL, RMASK, 0xf, true);
  return fmaxf(x, __int_as_float(y));
}

// ---------------- K3: fused instnorm finalize + sinkhorn (matrix scaling, early-exit) ----------
// R9: corrected residual r = |q*w*(T/N) - 1| fires at ~8 iters -> ~118 us. Unchanged.
__global__ __launch_bounds__(512) void k_sinkhorn(float* __restrict__ sbuf,
                                                  const float* __restrict__ stats,
                                                  const float* __restrict__ gptr,
                                                  const float* __restrict__ bptr) {
  __shared__ unsigned Epk23[400 * 64];
  __shared__ unsigned short Eu4[400 * 64];
  __shared__ float wl[320];
  __shared__ float qsum[320];
  __shared__ float albuf[400];
  __shared__ unsigned convs[2];
  const int b = blockIdx.x;
  const int tid = threadIdx.x;
  const int wv = tid >> 6;
  const int l = tid & 63;
  float* S = sbuf + (size_t)b * NDIM * TPAD;
  const float NT = 400.0f * 315.0f;
  const float mean = stats[2 * b] / NT;
  const float var = stats[2 * b + 1] / NT - mean * mean;
  const float inv = rsqrtf(var + 1e-5f);
  const float gamma = gptr[0], beta = bptr[0];
  const float alpha = gamma * inv;
  const float L2E = 1.4426950408889634f;
  const float a2 = alpha * L2E;
  const float d2 = (beta - mean * alpha) * L2E;
  const int nbase = wv * 50;
  const float TOL = 1e-4f;
  const float TN_RATIO = 315.0f / 400.0f;

  unsigned E01[50];
#pragma unroll
  for (int j = 0; j < 50; ++j) {
    const float* row = S + (size_t)(nbase + j) * TPAD;
    float e0 = __builtin_amdgcn_exp2f(fmaf(row[l], a2, d2));
    float e1 = __builtin_amdgcn_exp2f(fmaf(row[64 + l], a2, d2));
    float e2 = __builtin_amdgcn_exp2f(fmaf(row[128 + l], a2, d2));
    float e3 = __builtin_amdgcn_exp2f(fmaf(row[192 + l], a2, d2));
    E01[j] = pack2(e0, e1);
    Epk23[(nbase + j) * 64 + l] = pack2(e2, e3);
    float e4 = 0.0f;
    if (l < 59) e4 = __builtin_amdgcn_exp2f(fmaf(row[256 + l], a2, d2));
    Eu4[(nbase + j) * 64 + l] = (unsigned short)(rne_hi(e4) >> 16);
  }
  if (tid < 320) { wl[tid] = (tid < 315) ? 1.0f : 0.0f; qsum[tid] = 0.0f; }
  if (tid < 2) convs[tid] = 0u;
  __syncthreads();

  bool fin = false;
  for (int it = 0; it < NITER; ++it) {
    float w0 = wl[l], w1 = wl[64 + l], w2 = wl[128 + l], w3 = wl[192 + l], w4 = wl[256 + l];
    float q0 = 0.f, q1 = 0.f, q2 = 0.f, q3 = 0.f, q4 = 0.f;
#pragma unroll
    for (int jc = 0; jc < 10; ++jc) {
      float p[5], e2v[5], e3v[5], e4v[5];
#pragma unroll
      for (int u = 0; u < 5; ++u) {
        const int j = jc * 5 + u;
        unsigned v23 = Epk23[(nbase + j) * 64 + l];
        e2v[u] = unpk_lo(v23);
        e3v[u] = unpk_hi(v23);
        e4v[u] = __uint_as_float(((unsigned)Eu4[(nbase + j) * 64 + l]) << 16);
        float t = e4v[u] * w4;
        t = fmaf(e3v[u], w3, t);
        t = fmaf(e2v[u], w2, t);
        t = fmaf(unpk_hi(E01[j]), w1, t);
        p[u] = fmaf(unpk_lo(E01[j]), w0, t);
      }
      float aj[5];
#pragma unroll
      for (int u = 0; u < 5; ++u) p[u] = dppadd<0x111, 0xf>(p[u]);
#pragma unroll
      for (int u = 0; u < 5; ++u) p[u] = dppadd<0x112, 0xf>(p[u]);
#pragma unroll
      for (int u = 0; u < 5; ++u) p[u] = dppadd<0x114, 0xf>(p[u]);
#pragma unroll
      for (int u = 0; u < 5; ++u) p[u] = dppadd<0x118, 0xf>(p[u]);
#pragma unroll
      for (int u = 0; u < 5; ++u) p[u] = dppadd<0x142, 0xa>(p[u]);
#pragma unroll
      for (int u = 0; u < 5; ++u) p[u] = dppadd<0x143, 0xc>(p[u]);
#pragma unroll
      for (int u = 0; u < 5; ++u) {
        float r = __builtin_amdgcn_rcpf(p[u]);
        aj[u] = __int_as_float(__builtin_amdgcn_readlane(__float_as_int(r), 63));
      }
#pragma unroll
      for (int u = 0; u < 5; ++u) {
        const int j = jc * 5 + u;
        q0 = fmaf(unpk_lo(E01[j]), aj[u], q0);
        q1 = fmaf(unpk_hi(E01[j]), aj[u], q1);
        q2 = fmaf(e2v[u], aj[u], q2);
        q3 = fmaf(e3v[u], aj[u], q3);
        q4 = fmaf(e4v[u], aj[u], q4);
      }
      if (fin && l == 0) {
#pragma unroll
        for (int u = 0; u < 5; ++u) albuf[nbase + jc * 5 + u] = aj[u];
      }
    }
    atomicAdd(&qsum[l], q0);
    atomicAdd(&qsum[64 + l], q1);
    atomicAdd(&qsum[128 + l], q2);
    atomicAdd(&qsum[192 + l], q3);
    atomicAdd(&qsum[256 + l], q4);
    __syncthreads();
    if (tid < 320) {
      float q = qsum[tid];
      float r = 0.0f;
      if (tid < 315) {
        r = fabsf(fmaf(q * wl[tid], TN_RATIO, -1.0f));
        wl[tid] = __builtin_amdgcn_rcpf(q);
      }
      qsum[tid] = 0.0f;
      r = dppmax<0x111, 0xf>(r);
      r = dppmax<0x112, 0xf>(r);
      r = dppmax<0x114, 0xf>(r);
      r = dppmax<0x118, 0xf>(r);
      r = dppmax<0x142, 0xa>(r);
      r = dppmax<0x143, 0xc>(r);
      if (l == 63) atomicMax(&convs[it & 1], __float_as_uint(r));
    }
    __syncthreads();
    if (fin) break;
    float resid = __uint_as_float(convs[it & 1]);
    fin = (resid < TOL) || (it == NITER - 2);
    if (tid == 0) convs[(it + 1) & 1] = 0u;
  }

  {
    float w0 = wl[l], w1 = wl[64 + l], w2 = wl[128 + l], w3 = wl[192 + l], w4 = wl[256 + l];
#pragma unroll
    for (int j = 0; j < 50; ++j) {
      const float aj = albuf[nbase + j];
      unsigned v23 = Epk23[(nbase + j) * 64 + l];
      float e4 = __uint_as_float(((unsigned)Eu4[(nbase + j) * 64 + l]) << 16);
      float* row = S + (size_t)(nbase + j) * TPAD;
      row[l] = aj * unpk_lo(E01[j]) * w0;
      row[64 + l] = aj * unpk_hi(E01[j]) * w1;
      row[128 + l] = aj * unpk_lo(v23) * w2;
      row[192 + l] = aj * unpk_hi(v23) * w3;
      if (l < 59) row[256 + l] = aj * e4 * w4;
    }
  }
}

// ---------------- K4: f1[b][t][d] = sum_n s1[b][n][t] * F[b][n][d]  (TN bf16 MFMA) ----------
__global__ __launch_bounds__(256) void k_f1(const float* __restrict__ s1,
                                            const float* __restrict__ F,
                                            float* __restrict__ f1) {
  __shared__ unsigned short Abf[64 * LDH];  // [t][n]
  __shared__ unsigned short Bbf[64 * LDH];  // [d][n]
  const int tid = threadIdx.x, l = tid & 63, wv = tid >> 6;
  const int d0 = blockIdx.x * 64, t0 = blockIdx.y * 64, bz = blockIdx.z;
  const float* sb = s1 + (size_t)bz * NDIM * TPAD;
  const float* Fb = F + (size_t)bz * NDIM * DDIM;
  float* out = f1 + (size_t)bz * TDIM * DDIM;
  f32x4 acc[4] = {};
  const int col = tid & 31, g = tid >> 5;  // staging: K-index col (n), 8-row group g
  for (int k0 = 0; k0 < 416; k0 += 32) {  // 13 chunks cover K=400 (masked)
    int n = k0 + col;
    float4 a0 = make_float4(0.f, 0.f, 0.f, 0.f), a1 = a0, b0 = a0, b1 = a0;
    if (n < NDIM) {
      a0 = *(const float4*)(sb + (size_t)n * TPAD + t0 + g * 8);
      a1 = *(const float4*)(sb + (size_t)n * TPAD + t0 + g * 8 + 4);
      b0 = *(const float4*)(Fb + (size_t)n * DDIM + d0 + g * 8);
      b1 = *(const float4*)(Fb + (size_t)n * DDIM + d0 + g * 8 + 4);
    }
    float av[8] = {a0.x, a0.y, a0.z, a0.w, a1.x, a1.y, a1.z, a1.w};
    float bv[8] = {b0.x, b0.y, b0.z, b0.w, b1.x, b1.y, b1.z, b1.w};
#pragma unroll
    for (int i = 0; i < 8; ++i) {
      Abf[(g * 8 + i) * LDH + col] = bf1(av[i]);
      Bbf[(g * 8 + i) * LDH + col] = bf1(bv[i]);
    }
    __syncthreads();
    bf16x8 af = *(const bf16x8*)(&Abf[(wv * 16 + (l & 15)) * LDH + (l >> 4) * 8]);
#pragma unroll
    for (int c = 0; c < 4; ++c) {
      bf16x8 bf_ = *(const bf16x8*)(&Bbf[(c * 16 + (l & 15)) * LDH + (l >> 4) * 8]);
      acc[c] = __builtin_amdgcn_mfma_f32_16x16x32_bf16(af, bf_, acc[c], 0, 0, 0);
    }
    __syncthreads();
  }
#pragma unroll
  for (int c = 0; c < 4; ++c)
#pragma unroll
    for (int r = 0; r < 4; ++r) {
      int t = t0 + wv * 16 + ((l >> 4) << 2) + r;
      int d = d0 + c * 16 + (l & 15);
      if (t < TDIM) out[(size_t)t * DDIM + d] = acc[c][r];
    }
}

// ---------------- K5a: h[r][j] = relu(f1[r]. @ Wh_top + TB[r%315])  (bf16 MFMA) -------------
__global__ __launch_bounds__(256) void k_h(const float* __restrict__ f1,
                                           const float* __restrict__ Wh,
                                           const float* __restrict__ TB,
                                           float* __restrict__ hbuf) {
  __shared__ unsigned short Abf[64 * LDH];  // [r][d]
  __shared__ unsigned short Bbf[64 * LDH];  // [j][d]
  const int tid = threadIdx.x, l = tid & 63, wv = tid >> 6;
  const int j0 = blockIdx.x * 64, r0 = blockIdx.y * 64;
  const int RTOT = BDIM * TDIM;  // 10080
  f32x4 acc[4] = {};
  const int m = tid >> 2, kq = (tid & 3) * 8;  // A staging (K-contiguous)
  const int col = tid & 31, g = tid >> 5;      // B staging (transpose)
  for (int k0 = 0; k0 < 512; k0 += 32) {
    float4 v0 = make_float4(0.f, 0.f, 0.f, 0.f), v1 = v0;
    int r = r0 + m;
    if (r < RTOT) {
      v0 = *(const float4*)(f1 + (size_t)r * DDIM + k0 + kq);
      v1 = *(const float4*)(f1 + (size_t)r * DDIM + k0 + kq + 4);
    }
    unsigned pa[4] = {pack2(v0.x, v0.y), pack2(v0.z, v0.w), pack2(v1.x, v1.y), pack2(v1.z, v1.w)};
    *(uint4*)(&Abf[m * LDH + kq]) = make_uint4(pa[0], pa[1], pa[2], pa[3]);
    // B: Wh rows d = k0+col (always < 512), j contiguous
    float4 b0 = *(const float4*)(Wh + (size_t)(k0 + col) * HDIM + j0 + g * 8);
    float4 b1 = *(const float4*)(Wh + (size_t)(k0 + col) * HDIM + j0 + g * 8 + 4);
    float bv[8] = {b0.x, b0.y, b0.z, b0.w, b1.x, b1.y, b1.z, b1.w};
#pragma unroll
    for (int i = 0; i < 8; ++i) Bbf[(g * 8 + i) * LDH + col] = bf1(bv[i]);
    __syncthreads();
    bf16x8 af = *(const bf16x8*)(&Abf[(wv * 16 + (l & 15)) * LDH + (l >> 4) * 8]);
#pragma unroll
    for (int c = 0; c < 4; ++c) {
      bf16x8 bf_ = *(const bf16x8*)(&Bbf[(c * 16 + (l & 15)) * LDH + (l >> 4) * 8]);
      acc[c] = __builtin_amdgcn_mfma_f32_16x16x32_bf16(af, bf_, acc[c], 0, 0, 0);
    }
    __syncthreads();
  }
  int tmod[4];
#pragma unroll
  for (int r = 0; r < 4; ++r) {
    int rr = r0 + wv * 16 + ((l >> 4) << 2) + r;
    tmod[r] = rr % TDIM;
  }
#pragma unroll
  for (int c = 0; c < 4; ++c)
#pragma unroll
    for (int r = 0; r < 4; ++r) {
      int rr = r0 + wv * 16 + ((l >> 4) << 2) + r;
      int j = j0 + c * 16 + (l & 15);
      if (rr < RTOT) {
        float v = acc[c][r] + TB[(size_t)tmod[r] * HDIM + j];
        hbuf[(size_t)rr * HDIM + j] = fmaxf(v, 0.f);
      }
    }
}

// ---------------- K5b: pred[r] = h[r]. @ Wo + bo ----------------
__global__ void k_pred(const float* __restrict__ hbuf, const float* __restrict__ Wo,
                       const float* __restrict__ bo, float* __restrict__ out) {
  int tid = threadIdx.x;
  int wv = tid >> 6, l = tid & 63;
  int r = blockIdx.x * 4 + wv;
  float s = 0.f;
#pragma unroll
  for (int k = 0; k < 4; ++k)
    s = fmaf(hbuf[(size_t)r * 256 + 64 * k + l], Wo[64 * k + l], s);
#pragma unroll
  for (int m = 1; m <= 32; m <<= 1) s += __shfl_xor(s, m, 64);
  if (l == 0) out[r] = s + bo[0];
}

// ---------------- launch ----------------
extern "C" void kernel_launch(void* const* d_in, const int* in_sizes, int n_in,
                              void* d_out, int out_size, void* d_ws, size_t ws_size,
                              hipStream_t stream) {
  const float* F     = (const float*)d_in[0];
  const float* text  = (const float*)d_in[1];
  const float* A     = (const float*)d_in[2];
  const float* gamma = (const float*)d_in[3];
  const float* beta  = (const float*)d_in[4];
  const float* Wh    = (const float*)d_in[5];
  const float* bh    = (const float*)d_in[6];
  const float* Wo    = (const float*)d_in[7];
  const float* bo    = (const float*)d_in[8];
  float* out = (float*)d_out;
  char* ws = (char*)d_ws;
  float* tA    = (float*)(ws + OFS_TA);
  float* TB    = (float*)(ws + OFS_TB);
  float* stats = (float*)(ws + OFS_STATS);
  float* sbuf  = (float*)(ws + OFS_S);
  float* f1    = (float*)(ws + OFS_F1);
  float* hbuf  = (float*)(ws + OFS_H);

  hipMemsetAsync(stats, 0, BDIM * 2 * sizeof(float), stream);
  k_tA<<<dim3(8, 5), 256, 0, stream>>>(text, A, tA);
  k_TB<<<dim3(4, 5), 256, 0, stream>>>(text, Wh, bh, TB);
  k_s<<<dim3(5, 7, 32), 256, 0, stream>>>(F, tA, sbuf, stats);
  k_sinkhorn<<<dim3(32), 512, 0, stream>>>(sbuf, stats, gamma, beta);
  k_f1<<<dim3(8, 5, 32), 256, 0, stream>>>(sbuf, F, f1);
  k_h<<<dim3(4, 158), 256, 0, stream>>>(f1, Wh, TB, hbuf);
  k_pred<<<dim3(2520), 256, 0, stream>>>(hbuf, Wo, bo, out);
}

// Round 11
// 316.793 us; speedup vs baseline: 5.1336x; 1.1776x over previous
//
#include <hip/hip_runtime.h>

// Problem dims
#define BDIM 32
#define NDIM 400
#define TDIM 315
#define TPAD 320
#define DDIM 512
#define HDIM 256
#define NITER 100

// Workspace layout (bytes)
#define OFS_TA    0u          // tA[320][512] f32 = 655360
#define OFS_TB    1048576u    // TB[320][256] f32 = 327680   (text @ Wh_bot + bh)
#define OFS_STATS 1572864u    // stats[32][2] f32 = 256      (sum, sumsq per batch)
#define OFS_S     2097152u    // s[32][400][320] f32 = 16384000
#define OFS_F1    18874368u   // f1b[32][315][512] bf16 = 10321920
#define OFS_S1B   41943040u   // s1b[32][400][320] bf16 = 8192000

typedef __attribute__((ext_vector_type(8))) short bf16x8;
typedef __attribute__((ext_vector_type(4))) float f32x4;

// ---------------- bf16 pack/unpack (RNE) ----------------
__device__ __forceinline__ unsigned rne_hi(float x) {
  unsigned u = __float_as_uint(x);
  u += 0x7fffu + ((u >> 16) & 1u);
  return u & 0xffff0000u;
}
__device__ __forceinline__ unsigned pack2(float lo, float hi) {
  return (rne_hi(lo) >> 16) | rne_hi(hi);
}
__device__ __forceinline__ unsigned short bf1(float x) { return (unsigned short)(rne_hi(x) >> 16); }
__device__ __forceinline__ float unpk_lo(unsigned p) { return __uint_as_float(p << 16); }
__device__ __forceinline__ float unpk_hi(unsigned p) { return __uint_as_float(p & 0xffff0000u); }

// ---------------- DPP wave reduce helpers (VALU pipe, no LDS) ----------------
template <int CTRL, int RMASK>
__device__ __forceinline__ float dppadd(float x) {
  int y = __builtin_amdgcn_update_dpp(0, __float_as_int(x), CTRL, RMASK, 0xf, true);
  return x + __int_as_float(y);
}
template <int CTRL, int RMASK>
__device__ __forceinline__ float dppmax(float x) {
  int y = __builtin_amdgcn_update_dpp(0, __float_as_int(x), CTRL, RMASK, 0xf, true);
  return fmaxf(x, __int_as_float(y));
}

// ---------------- fp32 GEMM pieces (k_pre only) ----------------
__device__ __forceinline__ void mm_inner(const float* __restrict__ As, const float* __restrict__ Bs,
                                         float acc[4][4], int tm, int tn) {
#pragma unroll
  for (int k = 0; k < 32; ++k) {
    float4 a = *(const float4*)(As + k * 72 + tm * 4);
    float4 b = *(const float4*)(Bs + k * 72 + tn * 4);
    float ar[4] = {a.x, a.y, a.z, a.w};
    float br[4] = {b.x, b.y, b.z, b.w};
#pragma unroll
    for (int i = 0; i < 4; ++i)
#pragma unroll
      for (int j = 0; j < 4; ++j)
        acc[i][j] = fmaf(ar[i], br[j], acc[i][j]);
  }
}

__device__ __forceinline__ void stage_T(float* __restrict__ Xs, const float* __restrict__ X,
                                        int r0, int ld, int k0, int tid, int rmax) {
  int kq = tid & 7;
  int mb = tid >> 3;
#pragma unroll
  for (int p = 0; p < 2; ++p) {
    int mm = mb + 32 * p;
    int row = r0 + mm;
    float4 v = make_float4(0.f, 0.f, 0.f, 0.f);
    if (row < rmax) v = *(const float4*)(X + (size_t)row * ld + k0 + 4 * kq);
    Xs[(4 * kq + 0) * 72 + mm] = v.x;
    Xs[(4 * kq + 1) * 72 + mm] = v.y;
    Xs[(4 * kq + 2) * 72 + mm] = v.z;
    Xs[(4 * kq + 3) * 72 + mm] = v.w;
  }
}

__device__ __forceinline__ void stage_N(float* __restrict__ Ws, const float* __restrict__ W,
                                        int k0, int ld, int n0, int tid, int kmax) {
  int nq = tid & 15;
  int kk = tid >> 4;
#pragma unroll
  for (int p = 0; p < 2; ++p) {
    int k = kk + 16 * p;
    float4 v = make_float4(0.f, 0.f, 0.f, 0.f);
    if (k0 + k < kmax) v = *(const float4*)(W + (size_t)(k0 + k) * ld + n0 + 4 * nq);
    *(float4*)(Ws + k * 72 + 4 * nq) = v;
  }
}

// ---------------- K1: merged tA (z=0) + TB (z=1) — independent small GEMMs, one dispatch -----
__global__ void k_pre(const float* __restrict__ text, const float* __restrict__ A,
                      const float* __restrict__ Wh, const float* __restrict__ bh,
                      float* __restrict__ tA, float* __restrict__ TB) {
  __shared__ float Xs[32 * 72], Ys[32 * 72];
  int tid = threadIdx.x, tm = tid >> 4, tn = tid & 15;
  if (blockIdx.z == 0) {
    // tA[t][d] = sum_e text[t][e]*A[d][e]  (NT)
    int d0 = blockIdx.x * 64, t0 = blockIdx.y * 64;
    float acc[4][4] = {};
    for (int k0 = 0; k0 < 512; k0 += 32) {
      stage_T(Xs, text, t0, 512, k0, tid, TDIM);
      stage_T(Ys, A, d0, 512, k0, tid, 512);
      __syncthreads();
      mm_inner(Xs, Ys, acc, tm, tn);
      __syncthreads();
    }
#pragma unroll
    for (int i = 0; i < 4; ++i) {
      int t = t0 + tm * 4 + i;  // pad rows get zeros (Xs zero-filled)
      *(float4*)(tA + (size_t)t * 512 + d0 + tn * 4) =
          make_float4(acc[i][0], acc[i][1], acc[i][2], acc[i][3]);
    }
  } else {
    if (blockIdx.x >= 4) return;
    // TB[t][h] = text[t] @ Wh_bot + bh  (NN)
    int h0 = blockIdx.x * 64, t0 = blockIdx.y * 64;
    const float* Wb = Wh + 512 * 256;
    float acc[4][4] = {};
    for (int k0 = 0; k0 < 512; k0 += 32) {
      stage_T(Xs, text, t0, 512, k0, tid, TDIM);
      stage_N(Ys, Wb, k0, 256, h0, tid, 512);
      __syncthreads();
      mm_inner(Xs, Ys, acc, tm, tn);
      __syncthreads();
    }
#pragma unroll
    for (int i = 0; i < 4; ++i) {
      int t = t0 + tm * 4 + i;
      int h = h0 + tn * 4;
      *(float4*)(TB + (size_t)t * 256 + h) =
          make_float4(acc[i][0] + bh[h], acc[i][1] + bh[h + 1],
                      acc[i][2] + bh[h + 2], acc[i][3] + bh[h + 3]);
    }
  }
}

// ================= MFMA GEMMs: 64x64 tile, 256 thr (4 waves), 16x16x32 bf16 =================
// LDS operand layout [dim][k]: row stride 40 halves (80 B, 16B-aligned, <=2-way banks).
// A-frag: m=lane&15, k=(lane>>4)*8+j  (one ds_read_b128). B-frag symmetric (n=lane&15).
// D: col(lane&15)=B-dim, row((lane>>4)*4+reg)=A-dim  [verified mappings, guide §3].
#define LDH 40

// ---------------- K2: s[b][n][t] = F[b][n]. dot tA[t].  (NT bf16 MFMA) + instnorm stats -----
__global__ __launch_bounds__(256) void k_s(const float* __restrict__ F,
                                           const float* __restrict__ tA,
                                           float* __restrict__ s, float* __restrict__ stats) {
  __shared__ unsigned short Abf[64 * LDH];
  __shared__ unsigned short Bbf[64 * LDH];
  __shared__ float red[8];
  const int tid = threadIdx.x, l = tid & 63, wv = tid >> 6;
  const int t0 = blockIdx.x * 64, n0 = blockIdx.y * 64, bz = blockIdx.z;
  const float* Fb = F + (size_t)bz * NDIM * DDIM;
  float* sb = s + (size_t)bz * NDIM * TPAD;
  f32x4 acc[4] = {};
  const int m = tid >> 2, kq = (tid & 3) * 8;
  for (int k0 = 0; k0 < 512; k0 += 32) {
    float4 v0 = make_float4(0.f, 0.f, 0.f, 0.f), v1 = v0;
    int n = n0 + m;
    if (n < NDIM) {
      v0 = *(const float4*)(Fb + (size_t)n * DDIM + k0 + kq);
      v1 = *(const float4*)(Fb + (size_t)n * DDIM + k0 + kq + 4);
    }
    unsigned pa[4] = {pack2(v0.x, v0.y), pack2(v0.z, v0.w), pack2(v1.x, v1.y), pack2(v1.z, v1.w)};
    *(uint4*)(&Abf[m * LDH + kq]) = make_uint4(pa[0], pa[1], pa[2], pa[3]);
    float4 w0 = *(const float4*)(tA + (size_t)(t0 + m) * DDIM + k0 + kq);
    float4 w1 = *(const float4*)(tA + (size_t)(t0 + m) * DDIM + k0 + kq + 4);
    unsigned pb[4] = {pack2(w0.x, w0.y), pack2(w0.z, w0.w), pack2(w1.x, w1.y), pack2(w1.z, w1.w)};
    *(uint4*)(&Bbf[m * LDH + kq]) = make_uint4(pb[0], pb[1], pb[2], pb[3]);
    __syncthreads();
    bf16x8 af = *(const bf16x8*)(&Abf[(wv * 16 + (l & 15)) * LDH + (l >> 4) * 8]);
#pragma unroll
    for (int c = 0; c < 4; ++c) {
      bf16x8 bf_ = *(const bf16x8*)(&Bbf[(c * 16 + (l & 15)) * LDH + (l >> 4) * 8]);
      acc[c] = __builtin_amdgcn_mfma_f32_16x16x32_bf16(af, bf_, acc[c], 0, 0, 0);
    }
    __syncthreads();
  }
  float lsum = 0.f, lsq = 0.f;
#pragma unroll
  for (int c = 0; c < 4; ++c)
#pragma unroll
    for (int r = 0; r < 4; ++r) {
      int n = n0 + wv * 16 + ((l >> 4) << 2) + r;
      int t = t0 + c * 16 + (l & 15);
      if (n < NDIM && t < TDIM) {
        float v = acc[c][r];
        sb[(size_t)n * TPAD + t] = v;
        lsum += v;
        lsq = fmaf(v, v, lsq);
      }
    }
#pragma unroll
  for (int mm = 1; mm <= 32; mm <<= 1) {
    lsum += __shfl_xor(lsum, mm, 64);
    lsq += __shfl_xor(lsq, mm, 64);
  }
  if ((tid & 63) == 0) { red[wv * 2] = lsum; red[wv * 2 + 1] = lsq; }
  __syncthreads();
  if (tid == 0) {
    float S = red[0] + red[2] + red[4] + red[6];
    float Q = red[1] + red[3] + red[5] + red[7];
    atomicAdd(&stats[bz * 2], S);
    atomicAdd(&stats[bz * 2 + 1], Q);
  }
}

// ---------------- K3: fused instnorm finalize + sinkhorn (early-exit, bf16 s1 out) ----------
// R9: residual r = |q*w*(T/N) - 1| fires ~8 iters. TOL 1e-3 (error ~1e-4 rel, 40x under bf16-E
// noise). Epilogue writes s1 as BF16 (k_f1 quantizes anyway) — halves the 32-CU write traffic.
__global__ __launch_bounds__(512) void k_sinkhorn(const float* __restrict__ sbuf,
                                                  const float* __restrict__ stats,
                                                  const float* __restrict__ gptr,
                                                  const float* __restrict__ bptr,
                                                  unsigned short* __restrict__ s1b) {
  __shared__ unsigned Epk23[400 * 64];
  __shared__ unsigned short Eu4[400 * 64];
  __shared__ float wl[320];
  __shared__ float qsum[320];
  __shared__ float albuf[400];
  __shared__ unsigned convs[2];
  const int b = blockIdx.x;
  const int tid = threadIdx.x;
  const int wv = tid >> 6;
  const int l = tid & 63;
  const float* S = sbuf + (size_t)b * NDIM * TPAD;
  unsigned short* S1 = s1b + (size_t)b * NDIM * TPAD;
  const float NT = 400.0f * 315.0f;
  const float mean = stats[2 * b] / NT;
  const float var = stats[2 * b + 1] / NT - mean * mean;
  const float inv = rsqrtf(var + 1e-5f);
  const float gamma = gptr[0], beta = bptr[0];
  const float alpha = gamma * inv;
  const float L2E = 1.4426950408889634f;
  const float a2 = alpha * L2E;
  const float d2 = (beta - mean * alpha) * L2E;
  const int nbase = wv * 50;
  const float TOL = 1e-3f;
  const float TN_RATIO = 315.0f / 400.0f;

  unsigned E01[50];
#pragma unroll
  for (int j = 0; j < 50; ++j) {
    const float* row = S + (size_t)(nbase + j) * TPAD;
    float e0 = __builtin_amdgcn_exp2f(fmaf(row[l], a2, d2));
    float e1 = __builtin_amdgcn_exp2f(fmaf(row[64 + l], a2, d2));
    float e2 = __builtin_amdgcn_exp2f(fmaf(row[128 + l], a2, d2));
    float e3 = __builtin_amdgcn_exp2f(fmaf(row[192 + l], a2, d2));
    E01[j] = pack2(e0, e1);
    Epk23[(nbase + j) * 64 + l] = pack2(e2, e3);
    float e4 = 0.0f;
    if (l < 59) e4 = __builtin_amdgcn_exp2f(fmaf(row[256 + l], a2, d2));
    Eu4[(nbase + j) * 64 + l] = (unsigned short)(rne_hi(e4) >> 16);
  }
  if (tid < 320) { wl[tid] = (tid < 315) ? 1.0f : 0.0f; qsum[tid] = 0.0f; }
  if (tid < 2) convs[tid] = 0u;
  __syncthreads();

  bool fin = false;
  for (int it = 0; it < NITER; ++it) {
    float w0 = wl[l], w1 = wl[64 + l], w2 = wl[128 + l], w3 = wl[192 + l], w4 = wl[256 + l];
    float q0 = 0.f, q1 = 0.f, q2 = 0.f, q3 = 0.f, q4 = 0.f;
#pragma unroll
    for (int jc = 0; jc < 10; ++jc) {
      float p[5], e2v[5], e3v[5], e4v[5];
#pragma unroll
      for (int u = 0; u < 5; ++u) {
        const int j = jc * 5 + u;
        unsigned v23 = Epk23[(nbase + j) * 64 + l];
        e2v[u] = unpk_lo(v23);
        e3v[u] = unpk_hi(v23);
        e4v[u] = __uint_as_float(((unsigned)Eu4[(nbase + j) * 64 + l]) << 16);
        float t = e4v[u] * w4;
        t = fmaf(e3v[u], w3, t);
        t = fmaf(e2v[u], w2, t);
        t = fmaf(unpk_hi(E01[j]), w1, t);
        p[u] = fmaf(unpk_lo(E01[j]), w0, t);
      }
      float aj[5];
#pragma unroll
      for (int u = 0; u < 5; ++u) p[u] = dppadd<0x111, 0xf>(p[u]);
#pragma unroll
      for (int u = 0; u < 5; ++u) p[u] = dppadd<0x112, 0xf>(p[u]);
#pragma unroll
      for (int u = 0; u < 5; ++u) p[u] = dppadd<0x114, 0xf>(p[u]);
#pragma unroll
      for (int u = 0; u < 5; ++u) p[u] = dppadd<0x118, 0xf>(p[u]);
#pragma unroll
      for (int u = 0; u < 5; ++u) p[u] = dppadd<0x142, 0xa>(p[u]);
#pragma unroll
      for (int u = 0; u < 5; ++u) p[u] = dppadd<0x143, 0xc>(p[u]);
#pragma unroll
      for (int u = 0; u < 5; ++u) {
        float r = __builtin_amdgcn_rcpf(p[u]);
        aj[u] = __int_as_float(__builtin_amdgcn_readlane(__float_as_int(r), 63));
      }
#pragma unroll
      for (int u = 0; u < 5; ++u) {
        const int j = jc * 5 + u;
        q0 = fmaf(unpk_lo(E01[j]), aj[u], q0);
        q1 = fmaf(unpk_hi(E01[j]), aj[u], q1);
        q2 = fmaf(e2v[u], aj[u], q2);
        q3 = fmaf(e3v[u], aj[u], q3);
        q4 = fmaf(e4v[u], aj[u], q4);
      }
      if (fin && l == 0) {
#pragma unroll
        for (int u = 0; u < 5; ++u) albuf[nbase + jc * 5 + u] = aj[u];
      }
    }
    atomicAdd(&qsum[l], q0);
    atomicAdd(&qsum[64 + l], q1);
    atomicAdd(&qsum[128 + l], q2);
    atomicAdd(&qsum[192 + l], q3);
    atomicAdd(&qsum[256 + l], q4);
    __syncthreads();
    if (tid < 320) {
      float q = qsum[tid];
      float r = 0.0f;
      if (tid < 315) {
        r = fabsf(fmaf(q * wl[tid], TN_RATIO, -1.0f));
        wl[tid] = __builtin_amdgcn_rcpf(q);
      }
      qsum[tid] = 0.0f;
      r = dppmax<0x111, 0xf>(r);
      r = dppmax<0x112, 0xf>(r);
      r = dppmax<0x114, 0xf>(r);
      r = dppmax<0x118, 0xf>(r);
      r = dppmax<0x142, 0xa>(r);
      r = dppmax<0x143, 0xc>(r);
      if (l == 63) atomicMax(&convs[it & 1], __float_as_uint(r));
    }
    __syncthreads();
    if (fin) break;
    float resid = __uint_as_float(convs[it & 1]);
    fin = (resid < TOL) || (it == NITER - 2);
    if (tid == 0) convs[(it + 1) & 1] = 0u;
  }

  // epilogue: s1 = a_fin * E * w_fin, written BF16 (consumer k_f1 quantizes anyway)
  {
    float w0 = wl[l], w1 = wl[64 + l], w2 = wl[128 + l], w3 = wl[192 + l], w4 = wl[256 + l];
#pragma unroll
    for (int j = 0; j < 50; ++j) {
      const float aj = albuf[nbase + j];
      unsigned v23 = Epk23[(nbase + j) * 64 + l];
      float e4 = __uint_as_float(((unsigned)Eu4[(nbase + j) * 64 + l]) << 16);
      unsigned short* row = S1 + (size_t)(nbase + j) * TPAD;
      row[l] = bf1(aj * unpk_lo(E01[j]) * w0);
      row[64 + l] = bf1(aj * unpk_hi(E01[j]) * w1);
      row[128 + l] = bf1(aj * unpk_lo(v23) * w2);
      row[192 + l] = bf1(aj * unpk_hi(v23) * w3);
      row[256 + l] = (l < 59) ? bf1(aj * e4 * w4) : (unsigned short)0;  // zero pad cols 315..319
    }
  }
}

// ---------------- K4: f1[b][t][d] = sum_n s1[b][n][t] * F[b][n][d]  (TN bf16 MFMA) ----------
// A read directly from bf16 s1b (uint4 copy, no repack); output written bf16 (k_h quantizes).
__global__ __launch_bounds__(256) void k_f1(const unsigned short* __restrict__ s1b,
                                            const float* __restrict__ F,
                                            unsigned short* __restrict__ f1b) {
  __shared__ unsigned short Abf[64 * LDH];  // [t][n]
  __shared__ unsigned short Bbf[64 * LDH];  // [d][n]
  const int tid = threadIdx.x, l = tid & 63, wv = tid >> 6;
  const int d0 = blockIdx.x * 64, t0 = blockIdx.y * 64, bz = blockIdx.z;
  const unsigned short* sb = s1b + (size_t)bz * NDIM * TPAD;
  const float* Fb = F + (size_t)bz * NDIM * DDIM;
  unsigned short* out = f1b + (size_t)bz * TDIM * DDIM;
  f32x4 acc[4] = {};
  const int col = tid & 31, g = tid >> 5;
  for (int k0 = 0; k0 < 416; k0 += 32) {  // 13 chunks cover K=400 (masked)
    int n = k0 + col;
    // A: 8 bf16 of s1 row n, t-contiguous — one uint4
    uint4 av = make_uint4(0, 0, 0, 0);
    float4 b0 = make_float4(0.f, 0.f, 0.f, 0.f), b1 = b0;
    if (n < NDIM) {
      av = *(const uint4*)(sb + (size_t)n * TPAD + t0 + g * 8);
      b0 = *(const float4*)(Fb + (size_t)n * DDIM + d0 + g * 8);
      b1 = *(const float4*)(Fb + (size_t)n * DDIM + d0 + g * 8 + 4);
    }
    unsigned short ah[8];
    *(uint4*)ah = av;
    float bv[8] = {b0.x, b0.y, b0.z, b0.w, b1.x, b1.y, b1.z, b1.w};
#pragma unroll
    for (int i = 0; i < 8; ++i) {
      Abf[(g * 8 + i) * LDH + col] = ah[i];
      Bbf[(g * 8 + i) * LDH + col] = bf1(bv[i]);
    }
    __syncthreads();
    bf16x8 af = *(const bf16x8*)(&Abf[(wv * 16 + (l & 15)) * LDH + (l >> 4) * 8]);
#pragma unroll
    for (int c = 0; c < 4; ++c) {
      bf16x8 bf_ = *(const bf16x8*)(&Bbf[(c * 16 + (l & 15)) * LDH + (l >> 4) * 8]);
      acc[c] = __builtin_amdgcn_mfma_f32_16x16x32_bf16(af, bf_, acc[c], 0, 0, 0);
    }
    __syncthreads();
  }
#pragma unroll
  for (int c = 0; c < 4; ++c)
#pragma unroll
    for (int r = 0; r < 4; ++r) {
      int t = t0 + wv * 16 + ((l >> 4) << 2) + r;
      int d = d0 + c * 16 + (l & 15);
      if (t < TDIM) out[(size_t)t * DDIM + d] = bf1(acc[c][r]);
    }
}

// ---------------- K5: fused h + pred: per block 64 r x 64 j; partial pred via quad-reduce ----
// pred[r] = sum_j relu(f1[r]@Wh + TB[r%315])[j] * Wo[j] + bo. Each j-block atomicAdds its
// partial (out zeroed by memsetAsync; bo added by j-block 0). h never materialized.
__global__ __launch_bounds__(256) void k_hp(const unsigned short* __restrict__ f1b,
                                            const float* __restrict__ Wh,
                                            const float* __restrict__ TB,
                                            const float* __restrict__ Wo,
                                            const float* __restrict__ bo,
                                            float* __restrict__ out) {
  __shared__ unsigned short Abf[64 * LDH];  // [r][d]
  __shared__ unsigned short Bbf[64 * LDH];  // [j][d]
  __shared__ float Wos[64];
  const int tid = threadIdx.x, l = tid & 63, wv = tid >> 6;
  const int j0 = blockIdx.x * 64, r0 = blockIdx.y * 64;
  const int RTOT = BDIM * TDIM;  // 10080
  if (tid < 64) Wos[tid] = Wo[j0 + tid];
  f32x4 acc[4] = {};
  const int m = tid >> 2, kq = (tid & 3) * 8;  // A staging (K-contiguous bf16)
  const int col = tid & 31, g = tid >> 5;      // B staging (transpose)
  for (int k0 = 0; k0 < 512; k0 += 32) {
    uint4 av = make_uint4(0, 0, 0, 0);
    int r = r0 + m;
    if (r < RTOT) av = *(const uint4*)(f1b + (size_t)r * DDIM + k0 + kq);
    *(uint4*)(&Abf[m * LDH + kq]) = av;
    float4 b0 = *(const float4*)(Wh + (size_t)(k0 + col) * HDIM + j0 + g * 8);
    float4 b1 = *(const float4*)(Wh + (size_t)(k0 + col) * HDIM + j0 + g * 8 + 4);
    float bv[8] = {b0.x, b0.y, b0.z, b0.w, b1.x, b1.y, b1.z, b1.w};
#pragma unroll
    for (int i = 0; i < 8; ++i) Bbf[(g * 8 + i) * LDH + col] = bf1(bv[i]);
    __syncthreads();
    bf16x8 af = *(const bf16x8*)(&Abf[(wv * 16 + (l & 15)) * LDH + (l >> 4) * 8]);
#pragma unroll
    for (int c = 0; c < 4; ++c) {
      bf16x8 bf_ = *(const bf16x8*)(&Bbf[(c * 16 + (l & 15)) * LDH + (l >> 4) * 8]);
      acc[c] = __builtin_amdgcn_mfma_f32_16x16x32_bf16(af, bf_, acc[c], 0, 0, 0);
    }
    __syncthreads();
  }
  // epilogue: part[r] = sum_c relu(acc + TB)*Wo over this block's 64 j
  int tmod[4];
#pragma unroll
  for (int r = 0; r < 4; ++r) {
    int rr = r0 + wv * 16 + ((l >> 4) << 2) + r;
    tmod[r] = rr % TDIM;
  }
  float part[4] = {0.f, 0.f, 0.f, 0.f};
#pragma unroll
  for (int c = 0; c < 4; ++c) {
    int jl = c * 16 + (l & 15);
    float woc = Wos[jl];
#pragma unroll
    for (int r = 0; r < 4; ++r) {
      float v = acc[c][r] + TB[(size_t)tmod[r] * HDIM + j0 + jl];
      part[r] = fmaf(fmaxf(v, 0.f), woc, part[r]);
    }
  }
  // quad (16-lane row) reduction; lane l&15==15 holds the sum
#pragma unroll
  for (int r = 0; r < 4; ++r) part[r] = dppadd<0x111, 0xf>(part[r]);
#pragma unroll
  for (int r = 0; r < 4; ++r) part[r] = dppadd<0x112, 0xf>(part[r]);
#pragma unroll
  for (int r = 0; r < 4; ++r) part[r] = dppadd<0x114, 0xf>(part[r]);
#pragma unroll
  for (int r = 0; r < 4; ++r) part[r] = dppadd<0x118, 0xf>(part[r]);
  if ((l & 15) == 15) {
    float base = (j0 == 0) ? bo[0] : 0.0f;
#pragma unroll
    for (int r = 0; r < 4; ++r) {
      int rr = r0 + wv * 16 + ((l >> 4) << 2) + r;
      if (rr < RTOT) atomicAdd(&out[rr], part[r] + base);
    }
  }
}

// ---------------- launch ----------------
extern "C" void kernel_launch(void* const* d_in, const int* in_sizes, int n_in,
                              void* d_out, int out_size, void* d_ws, size_t ws_size,
                              hipStream_t stream) {
  const float* F     = (const float*)d_in[0];
  const float* text  = (const float*)d_in[1];
  const float* A     = (const float*)d_in[2];
  const float* gamma = (const float*)d_in[3];
  const float* beta  = (const float*)d_in[4];
  const float* Wh    = (const float*)d_in[5];
  const float* bh    = (const float*)d_in[6];
  const float* Wo    = (const float*)d_in[7];
  const float* bo    = (const float*)d_in[8];
  float* out = (float*)d_out;
  char* ws = (char*)d_ws;
  float* tA    = (float*)(ws + OFS_TA);
  float* TB    = (float*)(ws + OFS_TB);
  float* stats = (float*)(ws + OFS_STATS);
  float* sbuf  = (float*)(ws + OFS_S);
  unsigned short* f1b = (unsigned short*)(ws + OFS_F1);
  unsigned short* s1b = (unsigned short*)(ws + OFS_S1B);

  hipMemsetAsync(stats, 0, BDIM * 2 * sizeof(float), stream);
  hipMemsetAsync(out, 0, (size_t)out_size * sizeof(float), stream);  // d_out is poisoned 0xAA
  k_pre<<<dim3(8, 5, 2), 256, 0, stream>>>(text, A, Wh, bh, tA, TB);
  k_s<<<dim3(5, 7, 32), 256, 0, stream>>>(F, tA, sbuf, stats);
  k_sinkhorn<<<dim3(32), 512, 0, stream>>>(sbuf, stats, gamma, beta, s1b);
  k_f1<<<dim3(8, 5, 32), 256, 0, stream>>>(s1b, F, f1b);
  k_hp<<<dim3(4, 158), 256, 0, stream>>>(f1b, Wh, TB, Wo, bo, out);
}

// Round 12
// 293.976 us; speedup vs baseline: 5.5320x; 1.0776x over previous
//
#include <hip/hip_runtime.h>
#include <hip/hip_fp16.h>

// Problem dims
#define BDIM 32
#define NDIM 400
#define TDIM 315
#define TPAD 320
#define DDIM 512
#define HDIM 256
#define NITER 100

// Workspace layout (bytes)
#define OFS_TA    0u          // tA[320][512] f32 = 655360
#define OFS_TB    1048576u    // TB[320][256] f32 = 327680   (text @ Wh_bot + bh)
#define OFS_STATS 1572864u    // stats[32][2] f32 = 256      (sum, sumsq per batch)
#define OFS_S     2097152u    // s[32][400][320] fp16 = 8192000
#define OFS_F1    18874368u   // f1b[32][315][512] bf16 = 10321920
#define OFS_S1B   41943040u   // s1b[32][400][320] bf16 = 8192000

typedef __attribute__((ext_vector_type(8))) short bf16x8;
typedef __attribute__((ext_vector_type(4))) float f32x4;

// ---------------- bf16 pack/unpack (RNE) ----------------
__device__ __forceinline__ unsigned rne_hi(float x) {
  unsigned u = __float_as_uint(x);
  u += 0x7fffu + ((u >> 16) & 1u);
  return u & 0xffff0000u;
}
__device__ __forceinline__ unsigned pack2(float lo, float hi) {
  return (rne_hi(lo) >> 16) | rne_hi(hi);
}
__device__ __forceinline__ unsigned short bf1(float x) { return (unsigned short)(rne_hi(x) >> 16); }
__device__ __forceinline__ float unpk_lo(unsigned p) { return __uint_as_float(p << 16); }
__device__ __forceinline__ float unpk_hi(unsigned p) { return __uint_as_float(p & 0xffff0000u); }

// ---------------- DPP wave reduce helpers (VALU pipe, no LDS) ----------------
template <int CTRL, int RMASK>
__device__ __forceinline__ float dppadd(float x) {
  int y = __builtin_amdgcn_update_dpp(0, __float_as_int(x), CTRL, RMASK, 0xf, true);
  return x + __int_as_float(y);
}
template <int CTRL, int RMASK>
__device__ __forceinline__ float dppmax(float x) {
  int y = __builtin_amdgcn_update_dpp(0, __float_as_int(x), CTRL, RMASK, 0xf, true);
  return fmaxf(x, __int_as_float(y));
}

// ---------------- fp32 GEMM pieces (k_pre only) ----------------
__device__ __forceinline__ void mm_inner(const float* __restrict__ As, const float* __restrict__ Bs,
                                         float acc[4][4], int tm, int tn) {
#pragma unroll
  for (int k = 0; k < 32; ++k) {
    float4 a = *(const float4*)(As + k * 72 + tm * 4);
    float4 b = *(const float4*)(Bs + k * 72 + tn * 4);
    float ar[4] = {a.x, a.y, a.z, a.w};
    float br[4] = {b.x, b.y, b.z, b.w};
#pragma unroll
    for (int i = 0; i < 4; ++i)
#pragma unroll
      for (int j = 0; j < 4; ++j)
        acc[i][j] = fmaf(ar[i], br[j], acc[i][j]);
  }
}

__device__ __forceinline__ void stage_T(float* __restrict__ Xs, const float* __restrict__ X,
                                        int r0, int ld, int k0, int tid, int rmax) {
  int kq = tid & 7;
  int mb = tid >> 3;
#pragma unroll
  for (int p = 0; p < 2; ++p) {
    int mm = mb + 32 * p;
    int row = r0 + mm;
    float4 v = make_float4(0.f, 0.f, 0.f, 0.f);
    if (row < rmax) v = *(const float4*)(X + (size_t)row * ld + k0 + 4 * kq);
    Xs[(4 * kq + 0) * 72 + mm] = v.x;
    Xs[(4 * kq + 1) * 72 + mm] = v.y;
    Xs[(4 * kq + 2) * 72 + mm] = v.z;
    Xs[(4 * kq + 3) * 72 + mm] = v.w;
  }
}

__device__ __forceinline__ void stage_N(float* __restrict__ Ws, const float* __restrict__ W,
                                        int k0, int ld, int n0, int tid, int kmax) {
  int nq = tid & 15;
  int kk = tid >> 4;
#pragma unroll
  for (int p = 0; p < 2; ++p) {
    int k = kk + 16 * p;
    float4 v = make_float4(0.f, 0.f, 0.f, 0.f);
    if (k0 + k < kmax) v = *(const float4*)(W + (size_t)(k0 + k) * ld + n0 + 4 * nq);
    *(float4*)(Ws + k * 72 + 4 * nq) = v;
  }
}

// ---------------- K1: merged tA (z=0) + TB (z=1) — independent small GEMMs, one dispatch -----
__global__ void k_pre(const float* __restrict__ text, const float* __restrict__ A,
                      const float* __restrict__ Wh, const float* __restrict__ bh,
                      float* __restrict__ tA, float* __restrict__ TB) {
  __shared__ float Xs[32 * 72], Ys[32 * 72];
  int tid = threadIdx.x, tm = tid >> 4, tn = tid & 15;
  if (blockIdx.z == 0) {
    int d0 = blockIdx.x * 64, t0 = blockIdx.y * 64;
    float acc[4][4] = {};
    for (int k0 = 0; k0 < 512; k0 += 32) {
      stage_T(Xs, text, t0, 512, k0, tid, TDIM);
      stage_T(Ys, A, d0, 512, k0, tid, 512);
      __syncthreads();
      mm_inner(Xs, Ys, acc, tm, tn);
      __syncthreads();
    }
#pragma unroll
    for (int i = 0; i < 4; ++i) {
      int t = t0 + tm * 4 + i;  // pad rows get zeros (Xs zero-filled)
      *(float4*)(tA + (size_t)t * 512 + d0 + tn * 4) =
          make_float4(acc[i][0], acc[i][1], acc[i][2], acc[i][3]);
    }
  } else {
    if (blockIdx.x >= 4) return;
    int h0 = blockIdx.x * 64, t0 = blockIdx.y * 64;
    const float* Wb = Wh + 512 * 256;
    float acc[4][4] = {};
    for (int k0 = 0; k0 < 512; k0 += 32) {
      stage_T(Xs, text, t0, 512, k0, tid, TDIM);
      stage_N(Ys, Wb, k0, 256, h0, tid, 512);
      __syncthreads();
      mm_inner(Xs, Ys, acc, tm, tn);
      __syncthreads();
    }
#pragma unroll
    for (int i = 0; i < 4; ++i) {
      int t = t0 + tm * 4 + i;
      int h = h0 + tn * 4;
      *(float4*)(TB + (size_t)t * 256 + h) =
          make_float4(acc[i][0] + bh[h], acc[i][1] + bh[h + 1],
                      acc[i][2] + bh[h + 2], acc[i][3] + bh[h + 3]);
    }
  }
}

// ================= MFMA GEMMs: 64x64 tile, 256 thr (4 waves), 16x16x32 bf16 =================
#define LDH 40

// ---------------- K2: s[b][n][t] (fp16 out) + instnorm stats (fp32 accumulators) ------------
// s stored fp16: |s| <= ~120 << 65504; rel err 2^-11 amplifies to ~0.25% on E — below the
// 0.4% bf16-E quantization already present. Halves write + sinkhorn init read.
__global__ __launch_bounds__(256) void k_s(const float* __restrict__ F,
                                           const float* __restrict__ tA,
                                           __half* __restrict__ s, float* __restrict__ stats) {
  __shared__ unsigned short Abf[64 * LDH];
  __shared__ unsigned short Bbf[64 * LDH];
  __shared__ float red[8];
  const int tid = threadIdx.x, l = tid & 63, wv = tid >> 6;
  const int t0 = blockIdx.x * 64, n0 = blockIdx.y * 64, bz = blockIdx.z;
  const float* Fb = F + (size_t)bz * NDIM * DDIM;
  __half* sb = s + (size_t)bz * NDIM * TPAD;
  f32x4 acc[4] = {};
  const int m = tid >> 2, kq = (tid & 3) * 8;
  for (int k0 = 0; k0 < 512; k0 += 32) {
    float4 v0 = make_float4(0.f, 0.f, 0.f, 0.f), v1 = v0;
    int n = n0 + m;
    if (n < NDIM) {
      v0 = *(const float4*)(Fb + (size_t)n * DDIM + k0 + kq);
      v1 = *(const float4*)(Fb + (size_t)n * DDIM + k0 + kq + 4);
    }
    unsigned pa[4] = {pack2(v0.x, v0.y), pack2(v0.z, v0.w), pack2(v1.x, v1.y), pack2(v1.z, v1.w)};
    *(uint4*)(&Abf[m * LDH + kq]) = make_uint4(pa[0], pa[1], pa[2], pa[3]);
    float4 w0 = *(const float4*)(tA + (size_t)(t0 + m) * DDIM + k0 + kq);
    float4 w1 = *(const float4*)(tA + (size_t)(t0 + m) * DDIM + k0 + kq + 4);
    unsigned pb[4] = {pack2(w0.x, w0.y), pack2(w0.z, w0.w), pack2(w1.x, w1.y), pack2(w1.z, w1.w)};
    *(uint4*)(&Bbf[m * LDH + kq]) = make_uint4(pb[0], pb[1], pb[2], pb[3]);
    __syncthreads();
    bf16x8 af = *(const bf16x8*)(&Abf[(wv * 16 + (l & 15)) * LDH + (l >> 4) * 8]);
#pragma unroll
    for (int c = 0; c < 4; ++c) {
      bf16x8 bf_ = *(const bf16x8*)(&Bbf[(c * 16 + (l & 15)) * LDH + (l >> 4) * 8]);
      acc[c] = __builtin_amdgcn_mfma_f32_16x16x32_bf16(af, bf_, acc[c], 0, 0, 0);
    }
    __syncthreads();
  }
  float lsum = 0.f, lsq = 0.f;
#pragma unroll
  for (int c = 0; c < 4; ++c)
#pragma unroll
    for (int r = 0; r < 4; ++r) {
      int n = n0 + wv * 16 + ((l >> 4) << 2) + r;
      int t = t0 + c * 16 + (l & 15);
      if (n < NDIM && t < TDIM) {
        float v = acc[c][r];
        sb[(size_t)n * TPAD + t] = __float2half(v);
        lsum += v;
        lsq = fmaf(v, v, lsq);
      }
    }
#pragma unroll
  for (int mm = 1; mm <= 32; mm <<= 1) {
    lsum += __shfl_xor(lsum, mm, 64);
    lsq += __shfl_xor(lsq, mm, 64);
  }
  if ((tid & 63) == 0) { red[wv * 2] = lsum; red[wv * 2 + 1] = lsq; }
  __syncthreads();
  if (tid == 0) {
    float S = red[0] + red[2] + red[4] + red[6];
    float Q = red[1] + red[3] + red[5] + red[7];
    atomicAdd(&stats[bz * 2], S);
    atomicAdd(&stats[bz * 2 + 1], Q);
  }
}

// ---------------- K3: fused instnorm finalize + sinkhorn (early-exit, 1024 thr) -------------
// 1024 threads (16 waves, 4 waves/SIMD): R11's 512-thr version was ~5x latency-bound
// (10.6 us/iter vs ~2 us arithmetic; 2 waves/SIMD couldn't hide ds_read+DPP+readlane chains).
// Registers hold only E01[25] (25 VGPRs; stripes 2-4 in LDS since R7) -> no spill at the
// 128-VGPR cap (R2's 1024-thr failure was E[25][4]=100 regs + temps).
// Residual r = |q*w*(T/N)-1| (R9); TOL 1e-3; ends with one full iteration after trigger.
__global__ __launch_bounds__(1024) void k_sinkhorn(const __half* __restrict__ sbuf,
                                                   const float* __restrict__ stats,
                                                   const float* __restrict__ gptr,
                                                   const float* __restrict__ bptr,
                                                   unsigned short* __restrict__ s1b) {
  __shared__ unsigned Epk23[400 * 64];
  __shared__ unsigned short Eu4[400 * 64];
  __shared__ float wl[320];
  __shared__ float qsum[320];
  __shared__ float albuf[400];
  __shared__ unsigned convs[2];
  const int b = blockIdx.x;
  const int tid = threadIdx.x;
  const int wv = tid >> 6;           // 0..15
  const int l = tid & 63;
  const __half* S = sbuf + (size_t)b * NDIM * TPAD;
  unsigned short* S1 = s1b + (size_t)b * NDIM * TPAD;
  const float NT = 400.0f * 315.0f;
  const float mean = stats[2 * b] / NT;
  const float var = stats[2 * b + 1] / NT - mean * mean;
  const float inv = rsqrtf(var + 1e-5f);
  const float gamma = gptr[0], beta = bptr[0];
  const float alpha = gamma * inv;
  const float L2E = 1.4426950408889634f;
  const float a2 = alpha * L2E;
  const float d2 = (beta - mean * alpha) * L2E;
  const int nbase = wv * 25;         // 25 rows per wave
  const float TOL = 1e-3f;
  const float TN_RATIO = 315.0f / 400.0f;

  unsigned E01[25];
#pragma unroll
  for (int j = 0; j < 25; ++j) {
    const __half* row = S + (size_t)(nbase + j) * TPAD;
    float e0 = __builtin_amdgcn_exp2f(fmaf(__half2float(row[l]), a2, d2));
    float e1 = __builtin_amdgcn_exp2f(fmaf(__half2float(row[64 + l]), a2, d2));
    float e2 = __builtin_amdgcn_exp2f(fmaf(__half2float(row[128 + l]), a2, d2));
    float e3 = __builtin_amdgcn_exp2f(fmaf(__half2float(row[192 + l]), a2, d2));
    E01[j] = pack2(e0, e1);
    Epk23[(nbase + j) * 64 + l] = pack2(e2, e3);
    float e4 = 0.0f;
    if (l < 59) e4 = __builtin_amdgcn_exp2f(fmaf(__half2float(row[256 + l]), a2, d2));
    Eu4[(nbase + j) * 64 + l] = (unsigned short)(rne_hi(e4) >> 16);
  }
  if (tid < 320) { wl[tid] = (tid < 315) ? 1.0f : 0.0f; qsum[tid] = 0.0f; }
  if (tid < 2) convs[tid] = 0u;
  __syncthreads();

  bool fin = false;
  for (int it = 0; it < NITER; ++it) {
    float w0 = wl[l], w1 = wl[64 + l], w2 = wl[128 + l], w3 = wl[192 + l], w4 = wl[256 + l];
    float q0 = 0.f, q1 = 0.f, q2 = 0.f, q3 = 0.f, q4 = 0.f;
#pragma unroll
    for (int jc = 0; jc < 5; ++jc) {
      float p[5], e2v[5], e3v[5], e4v[5];
#pragma unroll
      for (int u = 0; u < 5; ++u) {
        const int j = jc * 5 + u;
        unsigned v23 = Epk23[(nbase + j) * 64 + l];
        e2v[u] = unpk_lo(v23);
        e3v[u] = unpk_hi(v23);
        e4v[u] = __uint_as_float(((unsigned)Eu4[(nbase + j) * 64 + l]) << 16);
        float t = e4v[u] * w4;
        t = fmaf(e3v[u], w3, t);
        t = fmaf(e2v[u], w2, t);
        t = fmaf(unpk_hi(E01[j]), w1, t);
        p[u] = fmaf(unpk_lo(E01[j]), w0, t);
      }
      float aj[5];
#pragma unroll
      for (int u = 0; u < 5; ++u) p[u] = dppadd<0x111, 0xf>(p[u]);
#pragma unroll
      for (int u = 0; u < 5; ++u) p[u] = dppadd<0x112, 0xf>(p[u]);
#pragma unroll
      for (int u = 0; u < 5; ++u) p[u] = dppadd<0x114, 0xf>(p[u]);
#pragma unroll
      for (int u = 0; u < 5; ++u) p[u] = dppadd<0x118, 0xf>(p[u]);
#pragma unroll
      for (int u = 0; u < 5; ++u) p[u] = dppadd<0x142, 0xa>(p[u]);
#pragma unroll
      for (int u = 0; u < 5; ++u) p[u] = dppadd<0x143, 0xc>(p[u]);
#pragma unroll
      for (int u = 0; u < 5; ++u) {
        float r = __builtin_amdgcn_rcpf(p[u]);
        aj[u] = __int_as_float(__builtin_amdgcn_readlane(__float_as_int(r), 63));
      }
#pragma unroll
      for (int u = 0; u < 5; ++u) {
        const int j = jc * 5 + u;
        q0 = fmaf(unpk_lo(E01[j]), aj[u], q0);
        q1 = fmaf(unpk_hi(E01[j]), aj[u], q1);
        q2 = fmaf(e2v[u], aj[u], q2);
        q3 = fmaf(e3v[u], aj[u], q3);
        q4 = fmaf(e4v[u], aj[u], q4);
      }
      if (fin && l == 0) {
#pragma unroll
        for (int u = 0; u < 5; ++u) albuf[nbase + jc * 5 + u] = aj[u];
      }
    }
    atomicAdd(&qsum[l], q0);
    atomicAdd(&qsum[64 + l], q1);
    atomicAdd(&qsum[128 + l], q2);
    atomicAdd(&qsum[192 + l], q3);
    atomicAdd(&qsum[256 + l], q4);
    __syncthreads();
    if (tid < 320) {
      float q = qsum[tid];
      float r = 0.0f;
      if (tid < 315) {
        r = fabsf(fmaf(q * wl[tid], TN_RATIO, -1.0f));
        wl[tid] = __builtin_amdgcn_rcpf(q);
      }
      qsum[tid] = 0.0f;
      r = dppmax<0x111, 0xf>(r);
      r = dppmax<0x112, 0xf>(r);
      r = dppmax<0x114, 0xf>(r);
      r = dppmax<0x118, 0xf>(r);
      r = dppmax<0x142, 0xa>(r);
      r = dppmax<0x143, 0xc>(r);
      if (l == 63) atomicMax(&convs[it & 1], __float_as_uint(r));
    }
    __syncthreads();
    if (fin) break;
    float resid = __uint_as_float(convs[it & 1]);
    fin = (resid < TOL) || (it == NITER - 2);
    if (tid == 0) convs[(it + 1) & 1] = 0u;
  }

  // epilogue: s1 = a_fin * E * w_fin, written BF16 (consumer k_f1 quantizes anyway)
  {
    float w0 = wl[l], w1 = wl[64 + l], w2 = wl[128 + l], w3 = wl[192 + l], w4 = wl[256 + l];
#pragma unroll
    for (int j = 0; j < 25; ++j) {
      const float aj = albuf[nbase + j];
      unsigned v23 = Epk23[(nbase + j) * 64 + l];
      float e4 = __uint_as_float(((unsigned)Eu4[(nbase + j) * 64 + l]) << 16);
      unsigned short* row = S1 + (size_t)(nbase + j) * TPAD;
      row[l] = bf1(aj * unpk_lo(E01[j]) * w0);
      row[64 + l] = bf1(aj * unpk_hi(E01[j]) * w1);
      row[128 + l] = bf1(aj * unpk_lo(v23) * w2);
      row[192 + l] = bf1(aj * unpk_hi(v23) * w3);
      row[256 + l] = (l < 59) ? bf1(aj * e4 * w4) : (unsigned short)0;
    }
  }
}

// ---------------- K4: f1[b][t][d] = sum_n s1[b][n][t] * F[b][n][d]  (TN bf16 MFMA) ----------
__global__ __launch_bounds__(256) void k_f1(const unsigned short* __restrict__ s1b,
                                            const float* __restrict__ F,
                                            unsigned short* __restrict__ f1b) {
  __shared__ unsigned short Abf[64 * LDH];  // [t][n]
  __shared__ unsigned short Bbf[64 * LDH];  // [d][n]
  const int tid = threadIdx.x, l = tid & 63, wv = tid >> 6;
  const int d0 = blockIdx.x * 64, t0 = blockIdx.y * 64, bz = blockIdx.z;
  const unsigned short* sb = s1b + (size_t)bz * NDIM * TPAD;
  const float* Fb = F + (size_t)bz * NDIM * DDIM;
  unsigned short* out = f1b + (size_t)bz * TDIM * DDIM;
  f32x4 acc[4] = {};
  const int col = tid & 31, g = tid >> 5;
  for (int k0 = 0; k0 < 416; k0 += 32) {
    int n = k0 + col;
    uint4 av = make_uint4(0, 0, 0, 0);
    float4 b0 = make_float4(0.f, 0.f, 0.f, 0.f), b1 = b0;
    if (n < NDIM) {
      av = *(const uint4*)(sb + (size_t)n * TPAD + t0 + g * 8);
      b0 = *(const float4*)(Fb + (size_t)n * DDIM + d0 + g * 8);
      b1 = *(const float4*)(Fb + (size_t)n * DDIM + d0 + g * 8 + 4);
    }
    unsigned short ah[8];
    *(uint4*)ah = av;
    float bv[8] = {b0.x, b0.y, b0.z, b0.w, b1.x, b1.y, b1.z, b1.w};
#pragma unroll
    for (int i = 0; i < 8; ++i) {
      Abf[(g * 8 + i) * LDH + col] = ah[i];
      Bbf[(g * 8 + i) * LDH + col] = bf1(bv[i]);
    }
    __syncthreads();
    bf16x8 af = *(const bf16x8*)(&Abf[(wv * 16 + (l & 15)) * LDH + (l >> 4) * 8]);
#pragma unroll
    for (int c = 0; c < 4; ++c) {
      bf16x8 bf_ = *(const bf16x8*)(&Bbf[(c * 16 + (l & 15)) * LDH + (l >> 4) * 8]);
      acc[c] = __builtin_amdgcn_mfma_f32_16x16x32_bf16(af, bf_, acc[c], 0, 0, 0);
    }
    __syncthreads();
  }
#pragma unroll
  for (int c = 0; c < 4; ++c)
#pragma unroll
    for (int r = 0; r < 4; ++r) {
      int t = t0 + wv * 16 + ((l >> 4) << 2) + r;
      int d = d0 + c * 16 + (l & 15);
      if (t < TDIM) out[(size_t)t * DDIM + d] = bf1(acc[c][r]);
    }
}

// ---------------- K5: fused h + pred ----------------
__global__ __launch_bounds__(256) void k_hp(const unsigned short* __restrict__ f1b,
                                            const float* __restrict__ Wh,
                                            const float* __restrict__ TB,
                                            const float* __restrict__ Wo,
                                            const float* __restrict__ bo,
                                            float* __restrict__ out) {
  __shared__ unsigned short Abf[64 * LDH];  // [r][d]
  __shared__ unsigned short Bbf[64 * LDH];  // [j][d]
  __shared__ float Wos[64];
  const int tid = threadIdx.x, l = tid & 63, wv = tid >> 6;
  const int j0 = blockIdx.x * 64, r0 = blockIdx.y * 64;
  const int RTOT = BDIM * TDIM;  // 10080
  if (tid < 64) Wos[tid] = Wo[j0 + tid];
  f32x4 acc[4] = {};
  const int m = tid >> 2, kq = (tid & 3) * 8;
  const int col = tid & 31, g = tid >> 5;
  for (int k0 = 0; k0 < 512; k0 += 32) {
    uint4 av = make_uint4(0, 0, 0, 0);
    int r = r0 + m;
    if (r < RTOT) av = *(const uint4*)(f1b + (size_t)r * DDIM + k0 + kq);
    *(uint4*)(&Abf[m * LDH + kq]) = av;
    float4 b0 = *(const float4*)(Wh + (size_t)(k0 + col) * HDIM + j0 + g * 8);
    float4 b1 = *(const float4*)(Wh + (size_t)(k0 + col) * HDIM + j0 + g * 8 + 4);
    float bv[8] = {b0.x, b0.y, b0.z, b0.w, b1.x, b1.y, b1.z, b1.w};
#pragma unroll
    for (int i = 0; i < 8; ++i) Bbf[(g * 8 + i) * LDH + col] = bf1(bv[i]);
    __syncthreads();
    bf16x8 af = *(const bf16x8*)(&Abf[(wv * 16 + (l & 15)) * LDH + (l >> 4) * 8]);
#pragma unroll
    for (int c = 0; c < 4; ++c) {
      bf16x8 bf_ = *(const bf16x8*)(&Bbf[(c * 16 + (l & 15)) * LDH + (l >> 4) * 8]);
      acc[c] = __builtin_amdgcn_mfma_f32_16x16x32_bf16(af, bf_, acc[c], 0, 0, 0);
    }
    __syncthreads();
  }
  int tmod[4];
#pragma unroll
  for (int r = 0; r < 4; ++r) {
    int rr = r0 + wv * 16 + ((l >> 4) << 2) + r;
    tmod[r] = rr % TDIM;
  }
  float part[4] = {0.f, 0.f, 0.f, 0.f};
#pragma unroll
  for (int c = 0; c < 4; ++c) {
    int jl = c * 16 + (l & 15);
    float woc = Wos[jl];
#pragma unroll
    for (int r = 0; r < 4; ++r) {
      float v = acc[c][r] + TB[(size_t)tmod[r] * HDIM + j0 + jl];
      part[r] = fmaf(fmaxf(v, 0.f), woc, part[r]);
    }
  }
#pragma unroll
  for (int r = 0; r < 4; ++r) part[r] = dppadd<0x111, 0xf>(part[r]);
#pragma unroll
  for (int r = 0; r < 4; ++r) part[r] = dppadd<0x112, 0xf>(part[r]);
#pragma unroll
  for (int r = 0; r < 4; ++r) part[r] = dppadd<0x114, 0xf>(part[r]);
#pragma unroll
  for (int r = 0; r < 4; ++r) part[r] = dppadd<0x118, 0xf>(part[r]);
  if ((l & 15) == 15) {
    float base = (j0 == 0) ? bo[0] : 0.0f;
#pragma unroll
    for (int r = 0; r < 4; ++r) {
      int rr = r0 + wv * 16 + ((l >> 4) << 2) + r;
      if (rr < RTOT) atomicAdd(&out[rr], part[r] + base);
    }
  }
}

// ---------------- launch ----------------
extern "C" void kernel_launch(void* const* d_in, const int* in_sizes, int n_in,
                              void* d_out, int out_size, void* d_ws, size_t ws_size,
                              hipStream_t stream) {
  const float* F     = (const float*)d_in[0];
  const float* text  = (const float*)d_in[1];
  const float* A     = (const float*)d_in[2];
  const float* gamma = (const float*)d_in[3];
  const float* beta  = (const float*)d_in[4];
  const float* Wh    = (const float*)d_in[5];
  const float* bh    = (const float*)d_in[6];
  const float* Wo    = (const float*)d_in[7];
  const float* bo    = (const float*)d_in[8];
  float* out = (float*)d_out;
  char* ws = (char*)d_ws;
  float* tA    = (float*)(ws + OFS_TA);
  float* TB    = (float*)(ws + OFS_TB);
  float* stats = (float*)(ws + OFS_STATS);
  __half* sbuf = (__half*)(ws + OFS_S);
  unsigned short* f1b = (unsigned short*)(ws + OFS_F1);
  unsigned short* s1b = (unsigned short*)(ws + OFS_S1B);

  hipMemsetAsync(stats, 0, BDIM * 2 * sizeof(float), stream);
  hipMemsetAsync(out, 0, (size_t)out_size * sizeof(float), stream);
  k_pre<<<dim3(8, 5, 2), 256, 0, stream>>>(text, A, Wh, bh, tA, TB);
  k_s<<<dim3(5, 7, 32), 256, 0, stream>>>(F, tA, sbuf, stats);
  k_sinkhorn<<<dim3(32), 1024, 0, stream>>>(sbuf, stats, gamma, beta, s1b);
  k_f1<<<dim3(8, 5, 32), 256, 0, stream>>>(s1b, F, f1b);
  k_hp<<<dim3(4, 158), 256, 0, stream>>>(f1b, Wh, TB, Wo, bo, out);
}

// Round 13
// 285.833 us; speedup vs baseline: 5.6897x; 1.0285x over previous
//
#include <hip/hip_runtime.h>
#include <hip/hip_fp16.h>

// Problem dims
#define BDIM 32
#define NDIM 400
#define TDIM 315
#define TPAD 320
#define DDIM 512
#define HDIM 256
#define NITER 100

// Workspace layout (bytes), tightly packed (~41 MB)
#define OFS_TAB   0u          // tAb bf16 [320][512] = 327680
#define OFS_TB    327680u     // TB f32 [320][256] = 327680
#define OFS_STATS 655360u     // stats[32][2] f32 = 256
#define OFS_WHB   655616u     // Whb bf16 [512][256] = 262144
#define OFS_S     1048576u    // s fp16 [32][400][320] = 8192000
#define OFS_S1B   9240576u    // s1b bf16 [32][400][320] = 8192000
#define OFS_F1    17432576u   // f1b bf16 [32][315][512] = 10321920
#define OFS_FB    27754496u   // Fb bf16 [32][400][512] = 13107200  (end 40861696)

typedef __attribute__((ext_vector_type(8))) short bf16x8;
typedef __attribute__((ext_vector_type(4))) float f32x4;

// ---------------- bf16 pack/unpack (RNE) ----------------
__device__ __forceinline__ unsigned rne_hi(float x) {
  unsigned u = __float_as_uint(x);
  u += 0x7fffu + ((u >> 16) & 1u);
  return u & 0xffff0000u;
}
__device__ __forceinline__ unsigned pack2(float lo, float hi) {
  return (rne_hi(lo) >> 16) | rne_hi(hi);
}
__device__ __forceinline__ unsigned short bf1(float x) { return (unsigned short)(rne_hi(x) >> 16); }
__device__ __forceinline__ float unpk_lo(unsigned p) { return __uint_as_float(p << 16); }
__device__ __forceinline__ float unpk_hi(unsigned p) { return __uint_as_float(p & 0xffff0000u); }

// ---------------- DPP wave reduce helpers (VALU pipe, no LDS) ----------------
template <int CTRL, int RMASK>
__device__ __forceinline__ float dppadd(float x) {
  int y = __builtin_amdgcn_update_dpp(0, __float_as_int(x), CTRL, RMASK, 0xf, true);
  return x + __int_as_float(y);
}
template <int CTRL, int RMASK>
__device__ __forceinline__ float dppmax(float x) {
  int y = __builtin_amdgcn_update_dpp(0, __float_as_int(x), CTRL, RMASK, 0xf, true);
  return fmaxf(x, __int_as_float(y));
}

// ---------------- K0: one-shot bf16 packing of F and Wh_top (grid-stride) -------------------
__global__ void k_pack(const float* __restrict__ F, const float* __restrict__ Wh,
                       unsigned short* __restrict__ Fb, unsigned short* __restrict__ Whb) {
  const int NF4 = (BDIM * NDIM * DDIM) / 4;  // 1638400
  const int NW4 = (DDIM * HDIM) / 4;         // 32768 (top half of Wh is the first 512*256)
  int stride = gridDim.x * blockDim.x;
  for (int i = blockIdx.x * blockDim.x + threadIdx.x; i < NF4; i += stride) {
    float4 v = ((const float4*)F)[i];
    ((uint2*)Fb)[i] = make_uint2(pack2(v.x, v.y), pack2(v.z, v.w));
  }
  for (int i = blockIdx.x * blockDim.x + threadIdx.x; i < NW4; i += stride) {
    float4 v = ((const float4*)Wh)[i];
    ((uint2*)Whb)[i] = make_uint2(pack2(v.x, v.y), pack2(v.z, v.w));
  }
}

// ---------------- fp32 GEMM pieces (k_pre only) ----------------
__device__ __forceinline__ void mm_inner(const float* __restrict__ As, const float* __restrict__ Bs,
                                         float acc[4][4], int tm, int tn) {
#pragma unroll
  for (int k = 0; k < 32; ++k) {
    float4 a = *(const float4*)(As + k * 72 + tm * 4);
    float4 b = *(const float4*)(Bs + k * 72 + tn * 4);
    float ar[4] = {a.x, a.y, a.z, a.w};
    float br[4] = {b.x, b.y, b.z, b.w};
#pragma unroll
    for (int i = 0; i < 4; ++i)
#pragma unroll
      for (int j = 0; j < 4; ++j)
        acc[i][j] = fmaf(ar[i], br[j], acc[i][j]);
  }
}

__device__ __forceinline__ void stage_T(float* __restrict__ Xs, const float* __restrict__ X,
                                        int r0, int ld, int k0, int tid, int rmax) {
  int kq = tid & 7;
  int mb = tid >> 3;
#pragma unroll
  for (int p = 0; p < 2; ++p) {
    int mm = mb + 32 * p;
    int row = r0 + mm;
    float4 v = make_float4(0.f, 0.f, 0.f, 0.f);
    if (row < rmax) v = *(const float4*)(X + (size_t)row * ld + k0 + 4 * kq);
    Xs[(4 * kq + 0) * 72 + mm] = v.x;
    Xs[(4 * kq + 1) * 72 + mm] = v.y;
    Xs[(4 * kq + 2) * 72 + mm] = v.z;
    Xs[(4 * kq + 3) * 72 + mm] = v.w;
  }
}

__device__ __forceinline__ void stage_N(float* __restrict__ Ws, const float* __restrict__ W,
                                        int k0, int ld, int n0, int tid, int kmax) {
  int nq = tid & 15;
  int kk = tid >> 4;
#pragma unroll
  for (int p = 0; p < 2; ++p) {
    int k = kk + 16 * p;
    float4 v = make_float4(0.f, 0.f, 0.f, 0.f);
    if (k0 + k < kmax) v = *(const float4*)(W + (size_t)(k0 + k) * ld + n0 + 4 * nq);
    *(float4*)(Ws + k * 72 + 4 * nq) = v;
  }
}

// ---------------- K1: merged tA (z=0, bf16 out) + TB (z=1) ----------------
__global__ void k_pre(const float* __restrict__ text, const float* __restrict__ A,
                      const float* __restrict__ Wh, const float* __restrict__ bh,
                      unsigned short* __restrict__ tAb, float* __restrict__ TB) {
  __shared__ float Xs[32 * 72], Ys[32 * 72];
  int tid = threadIdx.x, tm = tid >> 4, tn = tid & 15;
  if (blockIdx.z == 0) {
    int d0 = blockIdx.x * 64, t0 = blockIdx.y * 64;
    float acc[4][4] = {};
    for (int k0 = 0; k0 < 512; k0 += 32) {
      stage_T(Xs, text, t0, 512, k0, tid, TDIM);
      stage_T(Ys, A, d0, 512, k0, tid, 512);
      __syncthreads();
      mm_inner(Xs, Ys, acc, tm, tn);
      __syncthreads();
    }
#pragma unroll
    for (int i = 0; i < 4; ++i) {
      int t = t0 + tm * 4 + i;  // pad rows (>=315) get zeros (Xs zero-filled)
      *(uint2*)(tAb + (size_t)t * 512 + d0 + tn * 4) =
          make_uint2(pack2(acc[i][0], acc[i][1]), pack2(acc[i][2], acc[i][3]));
    }
  } else {
    if (blockIdx.x >= 4) return;
    int h0 = blockIdx.x * 64, t0 = blockIdx.y * 64;
    const float* Wb = Wh + 512 * 256;
    float acc[4][4] = {};
    for (int k0 = 0; k0 < 512; k0 += 32) {
      stage_T(Xs, text, t0, 512, k0, tid, TDIM);
      stage_N(Ys, Wb, k0, 256, h0, tid, 512);
      __syncthreads();
      mm_inner(Xs, Ys, acc, tm, tn);
      __syncthreads();
    }
#pragma unroll
    for (int i = 0; i < 4; ++i) {
      int t = t0 + tm * 4 + i;
      int h = h0 + tn * 4;
      *(float4*)(TB + (size_t)t * 256 + h) =
          make_float4(acc[i][0] + bh[h], acc[i][1] + bh[h + 1],
                      acc[i][2] + bh[h + 2], acc[i][3] + bh[h + 3]);
    }
  }
}

// ================= MFMA GEMMs: 64x64 tile, 256 thr (4 waves), 16x16x32 bf16 =================
#define LDH 40

// ---------------- K2: s[b][n][t] (fp16 out) + instnorm stats; operands pre-packed bf16 ------
__global__ __launch_bounds__(256) void k_s(const unsigned short* __restrict__ Fb,
                                           const unsigned short* __restrict__ tAb,
                                           __half* __restrict__ s, float* __restrict__ stats) {
  __shared__ unsigned short Abf[64 * LDH];
  __shared__ unsigned short Bbf[64 * LDH];
  __shared__ float red[8];
  const int tid = threadIdx.x, l = tid & 63, wv = tid >> 6;
  const int t0 = blockIdx.x * 64, n0 = blockIdx.y * 64, bz = blockIdx.z;
  const unsigned short* Fbb = Fb + (size_t)bz * NDIM * DDIM;
  __half* sb = s + (size_t)bz * NDIM * TPAD;
  f32x4 acc[4] = {};
  const int m = tid >> 2, kq = (tid & 3) * 8;
  for (int k0 = 0; k0 < 512; k0 += 32) {
    uint4 av = make_uint4(0, 0, 0, 0);
    int n = n0 + m;
    if (n < NDIM) av = *(const uint4*)(Fbb + (size_t)n * DDIM + k0 + kq);
    *(uint4*)(&Abf[m * LDH + kq]) = av;
    uint4 bv = *(const uint4*)(tAb + (size_t)(t0 + m) * DDIM + k0 + kq);
    *(uint4*)(&Bbf[m * LDH + kq]) = bv;
    __syncthreads();
    bf16x8 af = *(const bf16x8*)(&Abf[(wv * 16 + (l & 15)) * LDH + (l >> 4) * 8]);
#pragma unroll
    for (int c = 0; c < 4; ++c) {
      bf16x8 bf_ = *(const bf16x8*)(&Bbf[(c * 16 + (l & 15)) * LDH + (l >> 4) * 8]);
      acc[c] = __builtin_amdgcn_mfma_f32_16x16x32_bf16(af, bf_, acc[c], 0, 0, 0);
    }
    __syncthreads();
  }
  float lsum = 0.f, lsq = 0.f;
#pragma unroll
  for (int c = 0; c < 4; ++c)
#pragma unroll
    for (int r = 0; r < 4; ++r) {
      int n = n0 + wv * 16 + ((l >> 4) << 2) + r;
      int t = t0 + c * 16 + (l & 15);
      if (n < NDIM && t < TDIM) {
        float v = acc[c][r];
        sb[(size_t)n * TPAD + t] = __float2half(v);
        lsum += v;
        lsq = fmaf(v, v, lsq);
      }
    }
#pragma unroll
  for (int mm = 1; mm <= 32; mm <<= 1) {
    lsum += __shfl_xor(lsum, mm, 64);
    lsq += __shfl_xor(lsq, mm, 64);
  }
  if ((tid & 63) == 0) { red[wv * 2] = lsum; red[wv * 2 + 1] = lsq; }
  __syncthreads();
  if (tid == 0) {
    float S = red[0] + red[2] + red[4] + red[6];
    float Q = red[1] + red[3] + red[5] + red[7];
    atomicAdd(&stats[bz * 2], S);
    atomicAdd(&stats[bz * 2 + 1], Q);
  }
}

// ---------------- K3: fused instnorm finalize + sinkhorn (early-exit, 1024 thr) -------------
// Register relief vs R12: p-phase keeps PACKED v23 uints live (unpack is 1 VALU op per use),
// dropping the e2v/e3v float arrays (-10 VGPRs at the 64-reg cap). Residual |q*w*(T/N)-1|,
// TOL 1e-3; 'fin' runs one final full iteration that saves a (ends on col-norm like ref).
__global__ __launch_bounds__(1024) void k_sinkhorn(const __half* __restrict__ sbuf,
                                                   const float* __restrict__ stats,
                                                   const float* __restrict__ gptr,
                                                   const float* __restrict__ bptr,
                                                   unsigned short* __restrict__ s1b) {
  __shared__ unsigned Epk23[400 * 64];
  __shared__ unsigned short Eu4[400 * 64];
  __shared__ float wl[320];
  __shared__ float qsum[320];
  __shared__ float albuf[400];
  __shared__ unsigned convs[2];
  const int b = blockIdx.x;
  const int tid = threadIdx.x;
  const int wv = tid >> 6;           // 0..15
  const int l = tid & 63;
  const __half* S = sbuf + (size_t)b * NDIM * TPAD;
  unsigned short* S1 = s1b + (size_t)b * NDIM * TPAD;
  const float NT = 400.0f * 315.0f;
  const float mean = stats[2 * b] / NT;
  const float var = stats[2 * b + 1] / NT - mean * mean;
  const float inv = rsqrtf(var + 1e-5f);
  const float gamma = gptr[0], beta = bptr[0];
  const float alpha = gamma * inv;
  const float L2E = 1.4426950408889634f;
  const float a2 = alpha * L2E;
  const float d2 = (beta - mean * alpha) * L2E;
  const int nbase = wv * 25;         // 25 rows per wave
  const float TOL = 1e-3f;
  const float TN_RATIO = 315.0f / 400.0f;

  unsigned E01[25];
#pragma unroll
  for (int j = 0; j < 25; ++j) {
    const __half* row = S + (size_t)(nbase + j) * TPAD;
    float e0 = __builtin_amdgcn_exp2f(fmaf(__half2float(row[l]), a2, d2));
    float e1 = __builtin_amdgcn_exp2f(fmaf(__half2float(row[64 + l]), a2, d2));
    float e2 = __builtin_amdgcn_exp2f(fmaf(__half2float(row[128 + l]), a2, d2));
    float e3 = __builtin_amdgcn_exp2f(fmaf(__half2float(row[192 + l]), a2, d2));
    E01[j] = pack2(e0, e1);
    Epk23[(nbase + j) * 64 + l] = pack2(e2, e3);
    float e4 = 0.0f;
    if (l < 59) e4 = __builtin_amdgcn_exp2f(fmaf(__half2float(row[256 + l]), a2, d2));
    Eu4[(nbase + j) * 64 + l] = (unsigned short)(rne_hi(e4) >> 16);
  }
  if (tid < 320) { wl[tid] = (tid < 315) ? 1.0f : 0.0f; qsum[tid] = 0.0f; }
  if (tid < 2) convs[tid] = 0u;
  __syncthreads();

  bool fin = false;
  for (int it = 0; it < NITER; ++it) {
    float w0 = wl[l], w1 = wl[64 + l], w2 = wl[128 + l], w3 = wl[192 + l], w4 = wl[256 + l];
    float q0 = 0.f, q1 = 0.f, q2 = 0.f, q3 = 0.f, q4 = 0.f;
#pragma unroll
    for (int jc = 0; jc < 5; ++jc) {
      float p[5], e4v[5];
      unsigned v23[5];
#pragma unroll
      for (int u = 0; u < 5; ++u) {
        const int j = jc * 5 + u;
        v23[u] = Epk23[(nbase + j) * 64 + l];
        e4v[u] = __uint_as_float(((unsigned)Eu4[(nbase + j) * 64 + l]) << 16);
        float t = e4v[u] * w4;
        t = fmaf(unpk_hi(v23[u]), w3, t);
        t = fmaf(unpk_lo(v23[u]), w2, t);
        t = fmaf(unpk_hi(E01[j]), w1, t);
        p[u] = fmaf(unpk_lo(E01[j]), w0, t);
      }
      float aj[5];
#pragma unroll
      for (int u = 0; u < 5; ++u) p[u] = dppadd<0x111, 0xf>(p[u]);
#pragma unroll
      for (int u = 0; u < 5; ++u) p[u] = dppadd<0x112, 0xf>(p[u]);
#pragma unroll
      for (int u = 0; u < 5; ++u) p[u] = dppadd<0x114, 0xf>(p[u]);
#pragma unroll
      for (int u = 0; u < 5; ++u) p[u] = dppadd<0x118, 0xf>(p[u]);
#pragma unroll
      for (int u = 0; u < 5; ++u) p[u] = dppadd<0x142, 0xa>(p[u]);
#pragma unroll
      for (int u = 0; u < 5; ++u) p[u] = dppadd<0x143, 0xc>(p[u]);
#pragma unroll
      for (int u = 0; u < 5; ++u) {
        float r = __builtin_amdgcn_rcpf(p[u]);
        aj[u] = __int_as_float(__builtin_amdgcn_readlane(__float_as_int(r), 63));
      }
#pragma unroll
      for (int u = 0; u < 5; ++u) {
        const int j = jc * 5 + u;
        q0 = fmaf(unpk_lo(E01[j]), aj[u], q0);
        q1 = fmaf(unpk_hi(E01[j]), aj[u], q1);
        q2 = fmaf(unpk_lo(v23[u]), aj[u], q2);
        q3 = fmaf(unpk_hi(v23[u]), aj[u], q3);
        q4 = fmaf(e4v[u], aj[u], q4);
      }
      if (fin && l == 0) {
#pragma unroll
        for (int u = 0; u < 5; ++u) albuf[nbase + jc * 5 + u] = aj[u];
      }
    }
    atomicAdd(&qsum[l], q0);
    atomicAdd(&qsum[64 + l], q1);
    atomicAdd(&qsum[128 + l], q2);
    atomicAdd(&qsum[192 + l], q3);
    atomicAdd(&qsum[256 + l], q4);
    __syncthreads();
    if (tid < 320) {
      float q = qsum[tid];
      float r = 0.0f;
      if (tid < 315) {
        r = fabsf(fmaf(q * wl[tid], TN_RATIO, -1.0f));
        wl[tid] = __builtin_amdgcn_rcpf(q);
      }
      qsum[tid] = 0.0f;
      r = dppmax<0x111, 0xf>(r);
      r = dppmax<0x112, 0xf>(r);
      r = dppmax<0x114, 0xf>(r);
      r = dppmax<0x118, 0xf>(r);
      r = dppmax<0x142, 0xa>(r);
      r = dppmax<0x143, 0xc>(r);
      if (l == 63) atomicMax(&convs[it & 1], __float_as_uint(r));
    }
    __syncthreads();
    if (fin) break;
    float resid = __uint_as_float(convs[it & 1]);
    fin = (resid < TOL) || (it == NITER - 2);
    if (tid == 0) convs[(it + 1) & 1] = 0u;
  }

  // epilogue: s1 = a_fin * E * w_fin, written BF16 (consumer k_f1 quantizes anyway)
  {
    float w0 = wl[l], w1 = wl[64 + l], w2 = wl[128 + l], w3 = wl[192 + l], w4 = wl[256 + l];
#pragma unroll
    for (int j = 0; j < 25; ++j) {
      const float aj = albuf[nbase + j];
      unsigned v23 = Epk23[(nbase + j) * 64 + l];
      float e4 = __uint_as_float(((unsigned)Eu4[(nbase + j) * 64 + l]) << 16);
      unsigned short* row = S1 + (size_t)(nbase + j) * TPAD;
      row[l] = bf1(aj * unpk_lo(E01[j]) * w0);
      row[64 + l] = bf1(aj * unpk_hi(E01[j]) * w1);
      row[128 + l] = bf1(aj * unpk_lo(v23) * w2);
      row[192 + l] = bf1(aj * unpk_hi(v23) * w3);
      row[256 + l] = (l < 59) ? bf1(aj * e4 * w4) : (unsigned short)0;
    }
  }
}

// ---------------- K4: f1[b][t][d] = sum_n s1[b][n][t] * F[b][n][d]  (TN bf16 MFMA) ----------
__global__ __launch_bounds__(256) void k_f1(const unsigned short* __restrict__ s1b,
                                            const unsigned short* __restrict__ Fb,
                                            unsigned short* __restrict__ f1b) {
  __shared__ unsigned short Abf[64 * LDH];  // [t][n]
  __shared__ unsigned short Bbf[64 * LDH];  // [d][n]
  const int tid = threadIdx.x, l = tid & 63, wv = tid >> 6;
  const int d0 = blockIdx.x * 64, t0 = blockIdx.y * 64, bz = blockIdx.z;
  const unsigned short* sb = s1b + (size_t)bz * NDIM * TPAD;
  const unsigned short* Fbb = Fb + (size_t)bz * NDIM * DDIM;
  unsigned short* out = f1b + (size_t)bz * TDIM * DDIM;
  f32x4 acc[4] = {};
  const int col = tid & 31, g = tid >> 5;
  for (int k0 = 0; k0 < 416; k0 += 32) {
    int n = k0 + col;
    uint4 av = make_uint4(0, 0, 0, 0), bv = av;
    if (n < NDIM) {
      av = *(const uint4*)(sb + (size_t)n * TPAD + t0 + g * 8);
      bv = *(const uint4*)(Fbb + (size_t)n * DDIM + d0 + g * 8);
    }
    unsigned short ah[8], bh8[8];
    *(uint4*)ah = av;
    *(uint4*)bh8 = bv;
#pragma unroll
    for (int i = 0; i < 8; ++i) {
      Abf[(g * 8 + i) * LDH + col] = ah[i];
      Bbf[(g * 8 + i) * LDH + col] = bh8[i];
    }
    __syncthreads();
    bf16x8 af = *(const bf16x8*)(&Abf[(wv * 16 + (l & 15)) * LDH + (l >> 4) * 8]);
#pragma unroll
    for (int c = 0; c < 4; ++c) {
      bf16x8 bf_ = *(const bf16x8*)(&Bbf[(c * 16 + (l & 15)) * LDH + (l >> 4) * 8]);
      acc[c] = __builtin_amdgcn_mfma_f32_16x16x32_bf16(af, bf_, acc[c], 0, 0, 0);
    }
    __syncthreads();
  }
#pragma unroll
  for (int c = 0; c < 4; ++c)
#pragma unroll
    for (int r = 0; r < 4; ++r) {
      int t = t0 + wv * 16 + ((l >> 4) << 2) + r;
      int d = d0 + c * 16 + (l & 15);
      if (t < TDIM) out[(size_t)t * DDIM + d] = bf1(acc[c][r]);
    }
}

// ---------------- K5: fused h + pred (Wh pre-packed bf16) ----------------
__global__ __launch_bounds__(256) void k_hp(const unsigned short* __restrict__ f1b,
                                            const unsigned short* __restrict__ Whb,
                                            const float* __restrict__ TB,
                                            const float* __restrict__ Wo,
                                            const float* __restrict__ bo,
                                            float* __restrict__ out) {
  __shared__ unsigned short Abf[64 * LDH];  // [r][d]
  __shared__ unsigned short Bbf[64 * LDH];  // [j][d]
  __shared__ float Wos[64];
  const int tid = threadIdx.x, l = tid & 63, wv = tid >> 6;
  const int j0 = blockIdx.x * 64, r0 = blockIdx.y * 64;
  const int RTOT = BDIM * TDIM;  // 10080
  if (tid < 64) Wos[tid] = Wo[j0 + tid];
  f32x4 acc[4] = {};
  const int m = tid >> 2, kq = (tid & 3) * 8;
  const int col = tid & 31, g = tid >> 5;
  for (int k0 = 0; k0 < 512; k0 += 32) {
    uint4 av = make_uint4(0, 0, 0, 0);
    int r = r0 + m;
    if (r < RTOT) av = *(const uint4*)(f1b + (size_t)r * DDIM + k0 + kq);
    *(uint4*)(&Abf[m * LDH + kq]) = av;
    uint4 bv = *(const uint4*)(Whb + (size_t)(k0 + col) * HDIM + j0 + g * 8);
    unsigned short bh8[8];
    *(uint4*)bh8 = bv;
#pragma unroll
    for (int i = 0; i < 8; ++i) Bbf[(g * 8 + i) * LDH + col] = bh8[i];
    __syncthreads();
    bf16x8 af = *(const bf16x8*)(&Abf[(wv * 16 + (l & 15)) * LDH + (l >> 4) * 8]);
#pragma unroll
    for (int c = 0; c < 4; ++c) {
      bf16x8 bf_ = *(const bf16x8*)(&Bbf[(c * 16 + (l & 15)) * LDH + (l >> 4) * 8]);
      acc[c] = __builtin_amdgcn_mfma_f32_16x16x32_bf16(af, bf_, acc[c], 0, 0, 0);
    }
    __syncthreads();
  }
  int tmod[4];
#pragma unroll
  for (int r = 0; r < 4; ++r) {
    int rr = r0 + wv * 16 + ((l >> 4) << 2) + r;
    tmod[r] = rr % TDIM;
  }
  float part[4] = {0.f, 0.f, 0.f, 0.f};
#pragma unroll
  for (int c = 0; c < 4; ++c) {
    int jl = c * 16 + (l & 15);
    float woc = Wos[jl];
#pragma unroll
    for (int r = 0; r < 4; ++r) {
      float v = acc[c][r] + TB[(size_t)tmod[r] * HDIM + j0 + jl];
      part[r] = fmaf(fmaxf(v, 0.f), woc, part[r]);
    }
  }
#pragma unroll
  for (int r = 0; r < 4; ++r) part[r] = dppadd<0x111, 0xf>(part[r]);
#pragma unroll
  for (int r = 0; r < 4; ++r) part[r] = dppadd<0x112, 0xf>(part[r]);
#pragma unroll
  for (int r = 0; r < 4; ++r) part[r] = dppadd<0x114, 0xf>(part[r]);
#pragma unroll
  for (int r = 0; r < 4; ++r) part[r] = dppadd<0x118, 0xf>(part[r]);
  if ((l & 15) == 15) {
    float base = (j0 == 0) ? bo[0] : 0.0f;
#pragma unroll
    for (int r = 0; r < 4; ++r) {
      int rr = r0 + wv * 16 + ((l >> 4) << 2) + r;
      if (rr < RTOT) atomicAdd(&out[rr], part[r] + base);
    }
  }
}

// ---------------- launch ----------------
extern "C" void kernel_launch(void* const* d_in, const int* in_sizes, int n_in,
                              void* d_out, int out_size, void* d_ws, size_t ws_size,
                              hipStream_t stream) {
  const float* F     = (const float*)d_in[0];
  const float* text  = (const float*)d_in[1];
  const float* A     = (const float*)d_in[2];
  const float* gamma = (const float*)d_in[3];
  const float* beta  = (const float*)d_in[4];
  const float* Wh    = (const float*)d_in[5];
  const float* bh    = (const float*)d_in[6];
  const float* Wo    = (const float*)d_in[7];
  const float* bo    = (const float*)d_in[8];
  float* out = (float*)d_out;
  char* ws = (char*)d_ws;
  unsigned short* tAb = (unsigned short*)(ws + OFS_TAB);
  float* TB    = (float*)(ws + OFS_TB);
  float* stats = (float*)(ws + OFS_STATS);
  unsigned short* Whb = (unsigned short*)(ws + OFS_WHB);
  __half* sbuf = (__half*)(ws + OFS_S);
  unsigned short* s1b = (unsigned short*)(ws + OFS_S1B);
  unsigned short* f1b = (unsigned short*)(ws + OFS_F1);
  unsigned short* Fb  = (unsigned short*)(ws + OFS_FB);

  hipMemsetAsync(stats, 0, BDIM * 2 * sizeof(float), stream);
  hipMemsetAsync(out, 0, (size_t)out_size * sizeof(float), stream);
  k_pack<<<512, 256, 0, stream>>>(F, Wh, Fb, Whb);
  k_pre<<<dim3(8, 5, 2), 256, 0, stream>>>(text, A, Wh, bh, tAb, TB);
  k_s<<<dim3(5, 7, 32), 256, 0, stream>>>(Fb, tAb, sbuf, stats);
  k_sinkhorn<<<dim3(32), 1024, 0, stream>>>(sbuf, stats, gamma, beta, s1b);
  k_f1<<<dim3(8, 5, 32), 256, 0, stream>>>(s1b, Fb, f1b);
  k_hp<<<dim3(4, 158), 256, 0, stream>>>(f1b, Whb, TB, Wo, bo, out);
}